// Round 8
// baseline (1062.145 us; speedup 1.0000x reference)
//
#include <hip/hip_runtime.h>
#include <hip/hip_bf16.h>

// PSHGCN on MI355X — round 13:
//  * SpMM restructured: ONE ROW PER WAVE (was one row per 16-lane quarter).
//    Round-12 post-mortem: all 4 SpMMs ~100 µs, VALUBusy 55% with memory
//    headroom (2.9 vs 3.9 TB/s random path) — the wave ran at max-of-4
//    Poisson row lengths + divergent remainders (~35-40% masked waste).
//    Now: quarter q handles edges j+2q, j+2q+1 of the SAME row; trip count
//    is wave-uniform (scalar loop, no divergence); partials reduced via
//    shfl_xor(16,32). Boundary masks (val-zeroing) only in first/last step.
//    scv padded with 8 zeroed records so tail over-reads contribute 0.
//  * spmm_update_out: 1024-thr/16-wave blocks (wave=row) keeping the fused
//    16-row W2 tail; xs/wT LDS as before.
//  * dense front-end (MFMA), CSR build, place_edges unchanged from round 12.

typedef float f32x2 __attribute__((ext_vector_type(2)));
typedef float f32x4 __attribute__((ext_vector_type(4)));
typedef short bf16x8 __attribute__((ext_vector_type(8)));

__device__ inline unsigned short f2bf(float x) {
    unsigned b = __float_as_uint(x);
    unsigned r = (b + 0x7fffu + ((b >> 16) & 1u)) >> 16;
    return (unsigned short)r;
}
__device__ inline float bflo(unsigned u) { return __uint_as_float(u << 16); }
__device__ inline float bfhi(unsigned u) { return __uint_as_float(u & 0xffff0000u); }

// pack 4 floats -> 4 fp8 e4m3 bytes (a in byte0 .. d in byte3)
__device__ inline unsigned pk_fp8x4(float a, float b, float c, float d) {
    int v = __builtin_amdgcn_cvt_pk_fp8_f32(a, b, 0, false);
    v = __builtin_amdgcn_cvt_pk_fp8_f32(c, d, v, true);
    return (unsigned)v;
}

// ------- dense: Mt(bf16, transposed [n][k]) = (Wp @ W1)^T -------
__global__ __launch_bounds__(128) void fuse_w(const float* __restrict__ Wp0,
                                              const float* __restrict__ Wp1,
                                              const float* __restrict__ W1,
                                              unsigned short* __restrict__ Mt0,
                                              unsigned short* __restrict__ Mt1) {
    int m = blockIdx.x >> 7;
    int i = blockIdx.x & 127;           // row of M = k index
    const float* Wp = m ? Wp1 : Wp0;
    unsigned short* Mt = m ? Mt1 : Mt0;
    __shared__ float r[128];
    int t = threadIdx.x;
    r[t] = Wp[i * 128 + t];
    __syncthreads();
    float acc = 0.f;
    #pragma unroll 8
    for (int k = 0; k < 128; ++k) acc += r[k] * W1[k * 128 + t];
    Mt[t * 128 + i] = f2bf(acc);        // transposed store: Mt[n][k]
}

// ---- dense (MFMA): Xbf/X8 = normalize(relu(xin @ M + b1)) ----
__global__ __launch_bounds__(256) void gemm_relu_norm(const float* __restrict__ xin,
                                                      const unsigned short* __restrict__ Mt,
                                                      const float* __restrict__ b1,
                                                      unsigned short* __restrict__ xbf,
                                                      unsigned char* __restrict__ x8,
                                                      int nrows) {
    __shared__ char xsh[64 * 256];      // x hi bf16, swizzled 16B slots
    __shared__ char xsl[64 * 256];      // x lo bf16
    __shared__ char mts[128 * 256];     // Mt bf16 [n][k], swizzled
    int t = threadIdx.x;
    long row0 = (long)blockIdx.x * 64;
    int rows_this = nrows - (int)row0;
    if (rows_this > 64) rows_this = 64;

    // stage x: fp32 -> (hi, lo) bf16 split, 16B slots swizzled by row&7
    #pragma unroll
    for (int it = 0; it < 4; ++it) {
        int idx = it * 256 + t;
        int row = idx >> 4, slot = idx & 15;
        float4 v0 = {0.f, 0.f, 0.f, 0.f}, v1 = {0.f, 0.f, 0.f, 0.f};
        if (row < rows_this) {
            v0 = *(const float4*)(xin + (row0 + row) * 128 + slot * 8);
            v1 = *(const float4*)(xin + (row0 + row) * 128 + slot * 8 + 4);
        }
        float vv[8] = {v0.x, v0.y, v0.z, v0.w, v1.x, v1.y, v1.z, v1.w};
        unsigned hw[8], lw[8];
        #pragma unroll
        for (int j = 0; j < 8; ++j) {
            unsigned h = f2bf(vv[j]);
            float hv = __uint_as_float(h << 16);
            hw[j] = h;
            lw[j] = f2bf(vv[j] - hv);
        }
        uint4 ph, pl;
        ph.x = hw[0] | (hw[1] << 16); ph.y = hw[2] | (hw[3] << 16);
        ph.z = hw[4] | (hw[5] << 16); ph.w = hw[6] | (hw[7] << 16);
        pl.x = lw[0] | (lw[1] << 16); pl.y = lw[2] | (lw[3] << 16);
        pl.z = lw[4] | (lw[5] << 16); pl.w = lw[6] | (lw[7] << 16);
        int off = row * 256 + ((slot ^ (row & 7)) << 4);
        *(uint4*)&xsh[off] = ph;
        *(uint4*)&xsl[off] = pl;
    }
    // stage Mt (32 KB, L2-hot), same swizzle
    #pragma unroll
    for (int it = 0; it < 8; ++it) {
        int idx = it * 256 + t;
        int row = idx >> 4, slot = idx & 15;
        uint4 mv = ((const uint4*)Mt)[idx];
        *(uint4*)&mts[row * 256 + ((slot ^ (row & 7)) << 4)] = mv;
    }
    __syncthreads();

    int w = t >> 6;                 // wave id: rows w*16..w*16+15
    int lidx = t & 15;              // lane&15
    int grp = (t >> 4) & 3;         // lane>>4 within wave
    f32x4 acc[8];
    #pragma unroll
    for (int nt = 0; nt < 8; ++nt) acc[nt] = (f32x4){0.f, 0.f, 0.f, 0.f};

    #pragma unroll
    for (int ks = 0; ks < 4; ++ks) {
        int arow = w * 16 + lidx;
        int slot = ks * 4 + grp;
        bf16x8 ah = *(bf16x8*)&xsh[arow * 256 + ((slot ^ (arow & 7)) << 4)];
        bf16x8 al = *(bf16x8*)&xsl[arow * 256 + ((slot ^ (arow & 7)) << 4)];
        #pragma unroll
        for (int nt = 0; nt < 8; ++nt) {
            int brow = nt * 16 + lidx;
            bf16x8 bb = *(bf16x8*)&mts[brow * 256 + ((slot ^ (brow & 7)) << 4)];
            acc[nt] = __builtin_amdgcn_mfma_f32_16x16x32_bf16(al, bb, acc[nt], 0, 0, 0);
            acc[nt] = __builtin_amdgcn_mfma_f32_16x16x32_bf16(ah, bb, acc[nt], 0, 0, 0);
        }
    }

    float bias[8];
    #pragma unroll
    for (int nt = 0; nt < 8; ++nt) bias[nt] = b1[nt * 16 + lidx];

    // epilogue: relu -> mean/std (16-lane group = one row) -> z -> LDS (bf16)
    #pragma unroll
    for (int r = 0; r < 4; ++r) {
        int row_loc = w * 16 + grp * 4 + r;
        float v[8];
        float s = 0.f;
        #pragma unroll
        for (int nt = 0; nt < 8; ++nt) {
            float x = acc[nt][r] + bias[nt];
            x = x > 0.f ? x : 0.f;
            v[nt] = x;
            s += x;
        }
        s += __shfl_xor(s, 1); s += __shfl_xor(s, 2);
        s += __shfl_xor(s, 4); s += __shfl_xor(s, 8);
        float mean = s * (1.0f / 128.0f);
        float q = 0.f;
        #pragma unroll
        for (int nt = 0; nt < 8; ++nt) {
            float d = v[nt] - mean;
            v[nt] = d;
            q += d * d;
        }
        q += __shfl_xor(q, 1); q += __shfl_xor(q, 2);
        q += __shfl_xor(q, 4); q += __shfl_xor(q, 8);
        float inv = 0.f;
        if (q > 0.f) inv = 1.0f / sqrtf(q * (1.0f / 127.0f));
        #pragma unroll
        for (int nt = 0; nt < 8; ++nt)
            *(unsigned short*)&xsh[row_loc * 256 + (nt * 16 + lidx) * 2] = f2bf(v[nt] * inv);
    }
    __syncthreads();

    // coalesced writeout: bf16 row-linear + fp8 shadow
    #pragma unroll
    for (int it = 0; it < 4; ++it) {
        int idx = it * 256 + t;
        int row = idx >> 4, slot = idx & 15;
        if (row < rows_this) {
            uint4 zv = *(uint4*)&xsh[row * 256 + slot * 16];
            *(uint4*)(xbf + (row0 + row) * 128 + slot * 8) = zv;
            uint2 p8;
            p8.x = pk_fp8x4(bflo(zv.x), bfhi(zv.x), bflo(zv.y), bfhi(zv.y));
            p8.y = pk_fp8x4(bflo(zv.z), bfhi(zv.z), bflo(zv.w), bfhi(zv.w));
            *(uint2*)(x8 + (row0 + row) * 128 + slot * 8) = p8;
        }
    }
}

// ---------------- CSR build (unified, N rows, global cols) ----------------
__global__ __launch_bounds__(256) void count_rows(const int* __restrict__ rows, int E,
                                                  int* __restrict__ cnt) {
    int i = (blockIdx.x * 256 + threadIdx.x) * 4;
    if (i + 4 <= E) {
        int4 r = *(const int4*)(rows + i);
        atomicAdd(&cnt[r.x], 1);
        atomicAdd(&cnt[r.y], 1);
        atomicAdd(&cnt[r.z], 1);
        atomicAdd(&cnt[r.w], 1);
    } else {
        for (; i < E; ++i) atomicAdd(&cnt[rows[i]], 1);
    }
}

__global__ __launch_bounds__(256) void scan1(const int* __restrict__ cnt, int R,
                                             int* __restrict__ rp, int* __restrict__ bt) {
    __shared__ int lds[256];
    int t = threadIdx.x, b = blockIdx.x;
    int base = b * 4096 + t * 16;
    int v[16];
    int s = 0;
    #pragma unroll
    for (int i = 0; i < 16; ++i) {
        int idx = base + i;
        int c = (idx < R) ? cnt[idx] : 0;
        v[i] = s;
        s += c;
    }
    lds[t] = s;
    __syncthreads();
    for (int off = 1; off < 256; off <<= 1) {
        int x = (t >= off) ? lds[t - off] : 0;
        __syncthreads();
        lds[t] += x;
        __syncthreads();
    }
    int excl = lds[t] - s;
    #pragma unroll
    for (int i = 0; i < 16; ++i) {
        int idx = base + i;
        if (idx < R) rp[idx] = excl + v[i];
    }
    if (t == 0) bt[b] = lds[255];
}

__global__ __launch_bounds__(64) void scan2(const int* __restrict__ bt, int B,
                                            int* __restrict__ bo, int* __restrict__ rp,
                                            int R, int E2) {
    int t = threadIdx.x;
    int v = (t < B) ? bt[t] : 0;
    int inc = v;
    #pragma unroll
    for (int off = 1; off < 64; off <<= 1) {
        int y = __shfl_up(inc, off);
        if (t >= off) inc += y;
    }
    if (t < B) bo[t] = inc - v;
    if (t == 0) rp[R] = E2;
}

__global__ __launch_bounds__(256) void scan3(int* __restrict__ rp, const int* __restrict__ bo,
                                             int R) {
    int i = blockIdx.x * 256 + threadIdx.x;
    if (i < R) rp[i] = rp[i] + bo[i >> 12];
}

__global__ __launch_bounds__(256) void binit(const int* __restrict__ rp, int NR,
                                             int nbuck, int* __restrict__ bcur) {
    int b = blockIdx.x * 256 + threadIdx.x;
    if (b < nbuck) {
        int r = b << 9;
        if (r > NR) r = NR;
        bcur[b] = rp[r];
    }
}

// ---- phase 1: partition edges into 512-row buckets (L2-local writes) ----
__global__ __launch_bounds__(256) void partition_edges(const int* __restrict__ rows,
                                                       const int* __restrict__ cols,
                                                       const float* __restrict__ vals,
                                                       int E, int nbuck,
                                                       int* __restrict__ bcur,
                                                       int2* __restrict__ tmp) {
    __shared__ int hist[512];
    __shared__ int gbase[512];
    __shared__ int cnt2[512];
    int t = threadIdx.x;
    for (int b = t; b < nbuck; b += 256) { hist[b] = 0; cnt2[b] = 0; }
    __syncthreads();
    long base = (long)blockIdx.x * 4096;
    #pragma unroll
    for (int k = 0; k < 16; ++k) {
        long i = base + k * 256 + t;
        if (i < E) atomicAdd(&hist[rows[i] >> 9], 1);
    }
    __syncthreads();
    for (int b = t; b < nbuck; b += 256) {
        int h = hist[b];
        gbase[b] = h ? atomicAdd(&bcur[b], h) : 0;
    }
    __syncthreads();
    #pragma unroll
    for (int k = 0; k < 16; ++k) {
        long i = base + k * 256 + t;
        if (i < E) {
            int rl = rows[i];
            int b = rl >> 9;
            int rank = atomicAdd(&cnt2[b], 1);
            int2 rec;
            rec.x = ((rl - (b << 9)) << 18) | cols[i];
            rec.y = __float_as_int(vals[i]);
            tmp[gbase[b] + rank] = rec;
        }
    }
}

// ---- phase 2: exact-position scatter within one bucket, LDS atomics only ----
__global__ __launch_bounds__(1024) void place_edges(const int* __restrict__ rp,
                                                    const int2* __restrict__ tmp,
                                                    int NR,
                                                    int2* __restrict__ scv) {
    __shared__ int hist[512];
    __shared__ int hoff[512];
    int b = blockIdx.x;
    int srow = b << 9;
    int erow = srow + 512;
    if (erow > NR) erow = NR;
    int start = rp[srow], endp = rp[erow];
    int t = threadIdx.x;
    if (t < 512) hist[t] = 0;
    __syncthreads();

    for (int i = start + t; i < endp; i += 1024)
        atomicAdd(&hist[tmp[i].x >> 18], 1);
    __syncthreads();

    if (t < 512) hoff[t] = hist[t];
    __syncthreads();
    for (int off = 1; off < 512; off <<= 1) {
        int v = 0;
        if (t < 512 && t >= off) v = hoff[t - off];
        __syncthreads();
        if (t < 512) hoff[t] += v;
        __syncthreads();
    }
    if (t < 512) hoff[t] = start + hoff[t] - hist[t];
    __syncthreads();

    int i = start + t;
    for (; i + 3 * 1024 < endp; i += 4 * 1024) {
        int2 a0 = tmp[i];
        int2 a1 = tmp[i + 1024];
        int2 a2 = tmp[i + 2048];
        int2 a3 = tmp[i + 3072];
        int p0 = atomicAdd(&hoff[a0.x >> 18], 1);
        int p1 = atomicAdd(&hoff[a1.x >> 18], 1);
        int p2 = atomicAdd(&hoff[a2.x >> 18], 1);
        int p3 = atomicAdd(&hoff[a3.x >> 18], 1);
        int2 o0; o0.x = a0.x & 0x3ffff; o0.y = a0.y;
        int2 o1; o1.x = a1.x & 0x3ffff; o1.y = a1.y;
        int2 o2; o2.x = a2.x & 0x3ffff; o2.y = a2.y;
        int2 o3; o3.x = a3.x & 0x3ffff; o3.y = a3.y;
        scv[p0] = o0;
        scv[p1] = o1;
        scv[p2] = o2;
        scv[p3] = o3;
    }
    for (; i < endp; i += 1024) {
        int2 rec = tmp[i];
        int p = atomicAdd(&hoff[rec.x >> 18], 1);
        int2 o;
        o.x = rec.x & 0x3ffff;
        o.y = rec.y;
        scv[p] = o;
    }
}

// decode one fp8 row-segment (8 vals in uint2) and packed-fma into acc[4]
#define DEC_FMA(qq, vv) do {                                                        \
    f32x2 vp_ = {(vv), (vv)};                                                       \
    acc[0] = __builtin_elementwise_fma(vp_, __builtin_amdgcn_cvt_pk_f32_fp8((qq).x, false), acc[0]); \
    acc[1] = __builtin_elementwise_fma(vp_, __builtin_amdgcn_cvt_pk_f32_fp8((qq).x, true),  acc[1]); \
    acc[2] = __builtin_elementwise_fma(vp_, __builtin_amdgcn_cvt_pk_f32_fp8((qq).y, false), acc[2]); \
    acc[3] = __builtin_elementwise_fma(vp_, __builtin_amdgcn_cvt_pk_f32_fp8((qq).y, true),  acc[3]); \
} while (0)

// ---- SpMM row core: ONE ROW PER WAVE. quarter q takes edges b+2q, b+2q+1.
// Trip count wave-uniform; boundary edges val-zeroed (first/last step only).
// scv must be padded with 8 zeroed records past E2.
__device__ inline void spmm_row8(const int2* __restrict__ scv,
                                 const unsigned char* __restrict__ g8,
                                 int beg, int end, int q2, int f, bool kf,
                                 f32x2* acc) {
    int base = beg & ~1;
    int nst = (end - base + 7) >> 3;
    int b = base;
    for (int s = 0; s < nst; ++s, b += 8) {
        int4 sv = *(const int4*)(scv + b + q2);
        float v0 = __int_as_float(sv.y);
        float v1 = __int_as_float(sv.w);
        if (s == 0) {
            if (kf) v0 = 0.f;                 // beg odd: edge 'base' is stale
        }
        if (s == nst - 1) {
            int rem = end - b;                // 1..8 valid edges this step
            if (q2 >= rem) v0 = 0.f;
            if (q2 + 1 >= rem) v1 = 0.f;
        }
        uint2 g0 = *(const uint2*)(g8 + ((long)sv.x << 7) + f);
        uint2 g1 = *(const uint2*)(g8 + ((long)sv.z << 7) + f);
        DEC_FMA(g0, v0);
        DEC_FMA(g1, v1);
    }
}

// cross-quarter reduction: lanes l, l+16, l+32, l+48 hold partials of same feats
__device__ inline void qreduce(f32x2* acc) {
    #pragma unroll
    for (int i = 0; i < 4; ++i) {
        acc[i].x += __shfl_xor(acc[i].x, 16);
        acc[i].y += __shfl_xor(acc[i].y, 16);
        acc[i].x += __shfl_xor(acc[i].x, 32);
        acc[i].y += __shfl_xor(acc[i].y, 32);
    }
}

// h = M @ X : gathers X8 (fp8), writes h as bf16 (stream) + fp8 (gather copy)
__global__ __launch_bounds__(256) void spmm_plain(const int* __restrict__ rp,
                                                  const int2* __restrict__ scv,
                                                  const unsigned char* __restrict__ x8,
                                                  unsigned short* __restrict__ houtbf,
                                                  unsigned char* __restrict__ hout8,
                                                  int R) {
    int row = blockIdx.x * 4 + (threadIdx.x >> 6);
    if (row >= R) return;
    int lane = threadIdx.x & 63;
    int q = lane >> 4, f = (lane & 15) << 3;
    int beg = rp[row], end = rp[row + 1];
    f32x2 acc[4];
    #pragma unroll
    for (int i = 0; i < 4; ++i) acc[i] = (f32x2){0.f, 0.f};
    spmm_row8(scv, x8, beg, end, q * 2, f, (beg & 1) && (q == 0), acc);
    qreduce(acc);
    long o = ((long)row << 7) + f;
    if (q == 0) {
        uint4 ob;
        ob.x = (unsigned)f2bf(acc[0].x) | ((unsigned)f2bf(acc[0].y) << 16);
        ob.y = (unsigned)f2bf(acc[1].x) | ((unsigned)f2bf(acc[1].y) << 16);
        ob.z = (unsigned)f2bf(acc[2].x) | ((unsigned)f2bf(acc[2].y) << 16);
        ob.w = (unsigned)f2bf(acc[3].x) | ((unsigned)f2bf(acc[3].y) << 16);
        *(uint4*)(houtbf + o) = ob;
    } else if (q == 1) {
        uint2 o8;
        o8.x = pk_fp8x4(acc[0].x, acc[0].y, acc[1].x, acc[1].y);
        o8.y = pk_fp8x4(acc[2].x, acc[2].y, acc[3].x, acc[3].y);
        *(uint2*)(hout8 + o) = o8;
    }
}

// pass-1 update: X = c0*X + c_h[seg]*h + c_2nd[seg]*(M @ h)
__global__ __launch_bounds__(256) void spmm_update(const int* __restrict__ rp,
                                                   const int2* __restrict__ scv,
                                                   const unsigned char* __restrict__ h8,
                                                   const unsigned short* __restrict__ hbf,
                                                   unsigned short* __restrict__ Xbf,
                                                   unsigned char* __restrict__ X8,
                                                   const float* __restrict__ coe,
                                                   int ihA, int iaA, int ihP, int iaP,
                                                   int NA, int R) {
    int row = blockIdx.x * 4 + (threadIdx.x >> 6);
    if (row >= R) return;
    int lane = threadIdx.x & 63;
    int q = lane >> 4, f = (lane & 15) << 3;
    int beg = rp[row], end = rp[row + 1];
    f32x2 acc[4];
    #pragma unroll
    for (int i = 0; i < 4; ++i) acc[i] = (f32x2){0.f, 0.f};
    spmm_row8(scv, h8, beg, end, q * 2, f, (beg & 1) && (q == 0), acc);
    qreduce(acc);

    if (q < 2) {
        float c0 = coe[0];
        float ch = coe[row < NA ? ihA : ihP];
        float ca = coe[row < NA ? iaA : iaP];
        long o = ((long)row << 7) + f;
        uint4 xv = *(const uint4*)(Xbf + o);
        uint4 hs = *(const uint4*)(hbf + o);
        float r[8];
        r[0] = c0 * bflo(xv.x) + ch * bflo(hs.x) + ca * acc[0].x;
        r[1] = c0 * bfhi(xv.x) + ch * bfhi(hs.x) + ca * acc[0].y;
        r[2] = c0 * bflo(xv.y) + ch * bflo(hs.y) + ca * acc[1].x;
        r[3] = c0 * bfhi(xv.y) + ch * bfhi(hs.y) + ca * acc[1].y;
        r[4] = c0 * bflo(xv.z) + ch * bflo(hs.z) + ca * acc[2].x;
        r[5] = c0 * bfhi(xv.z) + ch * bfhi(hs.z) + ca * acc[2].y;
        r[6] = c0 * bflo(xv.w) + ch * bflo(hs.w) + ca * acc[3].x;
        r[7] = c0 * bfhi(xv.w) + ch * bfhi(hs.w) + ca * acc[3].y;
        if (q == 0) {
            uint4 ob;
            ob.x = (unsigned)f2bf(r[0]) | ((unsigned)f2bf(r[1]) << 16);
            ob.y = (unsigned)f2bf(r[2]) | ((unsigned)f2bf(r[3]) << 16);
            ob.z = (unsigned)f2bf(r[4]) | ((unsigned)f2bf(r[5]) << 16);
            ob.w = (unsigned)f2bf(r[6]) | ((unsigned)f2bf(r[7]) << 16);
            *(uint4*)(Xbf + o) = ob;
        } else {
            uint2 o8;
            o8.x = pk_fp8x4(r[0], r[1], r[2], r[3]);
            o8.y = pk_fp8x4(r[4], r[5], r[6], r[7]);
            *(uint2*)(X8 + o) = o8;
        }
    }
}

// pass-2 update fused with final GEMM: 1024-thr block, 16 waves = 16 rows
__global__ __launch_bounds__(1024) void spmm_update_out(const int* __restrict__ rp,
                                                        const int2* __restrict__ scv,
                                                        const unsigned char* __restrict__ h8,
                                                        const unsigned short* __restrict__ hbf,
                                                        const unsigned short* __restrict__ Xbf,
                                                        const float* __restrict__ coe,
                                                        const float* __restrict__ W2,
                                                        const float* __restrict__ b2,
                                                        float* __restrict__ out,
                                                        int ihA, int iaA, int ihP, int iaP,
                                                        int NA, int R) {
    __shared__ float xs[16 * 132];
    __shared__ float wT[16 * 132];   // wT[c][k] = W2[k][c]
    __shared__ float bs[16];
    int t = threadIdx.x;
    #pragma unroll
    for (int i = 0; i < 2; ++i) {
        int idx = i * 1024 + t;               // 2048 = 128*16
        wT[(idx & 15) * 132 + (idx >> 4)] = W2[idx];
    }
    if (t < 16) bs[t] = b2[t];

    int wv = t >> 6;                           // 0..15, wave = row
    int row = blockIdx.x * 16 + wv;
    int lane = t & 63;
    int q = lane >> 4, f = (lane & 15) << 3;
    if (row < R) {
        int beg = rp[row], end = rp[row + 1];
        f32x2 acc[4];
        #pragma unroll
        for (int i = 0; i < 4; ++i) acc[i] = (f32x2){0.f, 0.f};
        spmm_row8(scv, h8, beg, end, q * 2, f, (beg & 1) && (q == 0), acc);
        qreduce(acc);
        if (q == 0) {
            float c0 = coe[0];
            float ch = coe[row < NA ? ihA : ihP];
            float ca = coe[row < NA ? iaA : iaP];
            long o = ((long)row << 7) + f;
            uint4 xv = *(const uint4*)(Xbf + o);
            uint4 hs = *(const uint4*)(hbf + o);
            float* x = &xs[wv * 132 + f];
            x[0] = c0 * bflo(xv.x) + ch * bflo(hs.x) + ca * acc[0].x;
            x[1] = c0 * bfhi(xv.x) + ch * bfhi(hs.x) + ca * acc[0].y;
            x[2] = c0 * bflo(xv.y) + ch * bflo(hs.y) + ca * acc[1].x;
            x[3] = c0 * bfhi(xv.y) + ch * bfhi(hs.y) + ca * acc[1].y;
            x[4] = c0 * bflo(xv.z) + ch * bflo(hs.z) + ca * acc[2].x;
            x[5] = c0 * bfhi(xv.z) + ch * bfhi(hs.z) + ca * acc[2].y;
            x[6] = c0 * bflo(xv.w) + ch * bflo(hs.w) + ca * acc[3].x;
            x[7] = c0 * bfhi(xv.w) + ch * bfhi(hs.w) + ca * acc[3].y;
        }
    }
    __syncthreads();
    if (t < 256) {
        int orl = t >> 4, c = t & 15;
        long orow = (long)blockIdx.x * 16 + orl;
        if (orow < R) {
            const float* xrow = &xs[orl * 132];
            const float* wrow = &wT[c * 132];
            f32x4 a4 = {0.f, 0.f, 0.f, 0.f};
            #pragma unroll 8
            for (int k = 0; k < 128; k += 4) {
                f32x4 xv = *(const f32x4*)(xrow + k);
                f32x4 wv2 = *(const f32x4*)(wrow + k);
                a4 = __builtin_elementwise_fma(xv, wv2, a4);
            }
            out[orow * 16 + c] = a4.x + a4.y + a4.z + a4.w + bs[c];
        }
    }
}

extern "C" void kernel_launch(void* const* d_in, const int* in_sizes, int n_in,
                              void* d_out, int out_size, void* d_ws, size_t ws_size,
                              hipStream_t stream) {
    const float* x0  = (const float*)d_in[0];
    const float* x1  = (const float*)d_in[1];
    const float* vap = (const float*)d_in[2];
    const float* vpa = (const float*)d_in[3];
    const int*   rap = (const int*)d_in[4];
    const int*   cap = (const int*)d_in[5];
    const int*   rpa = (const int*)d_in[6];
    const int*   cpa = (const int*)d_in[7];
    const float* Wp0 = (const float*)d_in[8];
    const float* Wp1 = (const float*)d_in[9];
    const float* W1  = (const float*)d_in[10];
    const float* b1  = (const float*)d_in[11];
    const float* W2  = (const float*)d_in[12];
    const float* b2  = (const float*)d_in[13];
    const float* coe = (const float*)d_in[14];
    float* out = (float*)d_out;

    const int NA = in_sizes[0] / 128;
    const int NP = in_sizes[1] / 128;
    const int N  = NA + NP;
    const int E  = in_sizes[2];
    const int E2 = 2 * E;

    char* p = (char*)d_ws;
    auto alloc = [&](size_t bytes) {
        char* r = p;
        p += (bytes + 255) & ~(size_t)255;
        return r;
    };
    unsigned short* Xbf = (unsigned short*)alloc((size_t)N * 128 * 2);
    unsigned short* hbf = (unsigned short*)alloc((size_t)N * 128 * 2);
    unsigned char* X8 = (unsigned char*)alloc((size_t)N * 128);
    unsigned char* h8 = (unsigned char*)alloc((size_t)N * 128);
    unsigned short* Mt0 = (unsigned short*)alloc(128 * 128 * 2);
    unsigned short* Mt1 = (unsigned short*)alloc(128 * 128 * 2);
    int* cnt   = (int*)alloc((size_t)N * 4);
    int* rp    = (int*)alloc((size_t)(N + 1) * 4);
    int* bt    = (int*)alloc(64 * 4);
    int* bo    = (int*)alloc(64 * 4);
    int2* scv  = (int2*)alloc(((size_t)E2 + 8) * 8);   // +8 zero-pad records
    int* bcur  = (int*)alloc(512 * 4);
    if ((size_t)(p - (char*)d_ws) > ws_size) return;

    // tmp partition buffer aliases Xbf (Xbf written only after CSR build);
    // E2*8 = 32 MB <= N*256B = 64 MB
    int2* tmp = (int2*)Xbf;

    const int nbuck = (N + 511) >> 9;
    const int pg = (E + 4095) / 4096;

    // ---- unified CSR build ----
    hipMemsetAsync(cnt, 0, (size_t)N * 4, stream);
    hipMemsetAsync(scv + E2, 0, 8 * sizeof(int2), stream);  // tail pad
    const int cg = (E / 4 + 255) / 256;
    count_rows<<<cg, 256, 0, stream>>>(rap, E, cnt);
    count_rows<<<cg, 256, 0, stream>>>(rpa, E, cnt);
    int B = (N + 4095) / 4096;
    scan1<<<B, 256, 0, stream>>>(cnt, N, rp, bt);
    scan2<<<1, 64, 0, stream>>>(bt, B, bo, rp, N, E2);
    scan3<<<(N + 255) / 256, 256, 0, stream>>>(rp, bo, N);
    binit<<<2, 256, 0, stream>>>(rp, N, nbuck, bcur);
    partition_edges<<<pg, 256, 0, stream>>>(rap, cap, vap, E, nbuck, bcur, tmp);
    partition_edges<<<pg, 256, 0, stream>>>(rpa, cpa, vpa, E, nbuck, bcur, tmp);
    place_edges<<<nbuck, 1024, 0, stream>>>(rp, tmp, N, scv);

    // ---- dense front-end (MFMA; Xbf written AFTER tmp aliasing done) ----
    fuse_w<<<256, 128, 0, stream>>>(Wp0, Wp1, W1, Mt0, Mt1);
    gemm_relu_norm<<<(NA + 63) / 64, 256, 0, stream>>>(x0, Mt0, b1, Xbf, X8, NA);
    gemm_relu_norm<<<(NP + 63) / 64, 256, 0, stream>>>(
        x1, Mt1, b1, Xbf + (size_t)NA * 128, X8 + (size_t)NA * 128, NP);

    const int sg4  = (N + 3) / 4;
    const int sg16 = (N + 15) / 16;

    // ---- pass 1 (AP first): A rows coe1/coe3, P rows coe2/coe4 ----
    spmm_plain<<<sg4, 256, 0, stream>>>(rp, scv, X8, hbf, h8, N);
    spmm_update<<<sg4, 256, 0, stream>>>(rp, scv, h8, hbf, Xbf, X8, coe, 1, 3, 2, 4, NA, N);

    // ---- pass 2 (PA first) fused with out = res2 @ W2 + b2 ----
    spmm_plain<<<sg4, 256, 0, stream>>>(rp, scv, X8, hbf, h8, N);
    spmm_update_out<<<sg16, 1024, 0, stream>>>(rp, scv, h8, hbf, Xbf, coe,
                                               W2, b2, out, 2, 4, 1, 3, NA, N);
}

// Round 9
// 978.468 us; speedup vs baseline: 1.0855x; 1.0855x over previous
//
#include <hip/hip_runtime.h>
#include <hip/hip_bf16.h>

// PSHGCN on MI355X — round 14:
//  * REVERT round-13's one-row-per-wave SpMM (fetch-rate collapsed 2.9->1.8
//    TB/s: 8 lines in flight vs 32 — MLP matters more than divergence).
//    Back to round-12 structure: one row per 16-lane quarter, unroll x8.
//  * NEW: degree-sorted row assignment. 64-bucket counting sort of rows by
//    CSR degree (two-pass LDS histogram, partition_edges pattern) -> the 4
//    rows sharing a wave have near-equal length -> max-of-4 waste (~30%)
//    gone. Per-row arithmetic identical -> bitwise-same output as round 12.
//  * dense front-end (MFMA), CSR build, place_edges unchanged.

typedef float f32x2 __attribute__((ext_vector_type(2)));
typedef float f32x4 __attribute__((ext_vector_type(4)));
typedef short bf16x8 __attribute__((ext_vector_type(8)));

__device__ inline unsigned short f2bf(float x) {
    unsigned b = __float_as_uint(x);
    unsigned r = (b + 0x7fffu + ((b >> 16) & 1u)) >> 16;
    return (unsigned short)r;
}
__device__ inline float bflo(unsigned u) { return __uint_as_float(u << 16); }
__device__ inline float bfhi(unsigned u) { return __uint_as_float(u & 0xffff0000u); }

// pack 4 floats -> 4 fp8 e4m3 bytes (a in byte0 .. d in byte3)
__device__ inline unsigned pk_fp8x4(float a, float b, float c, float d) {
    int v = __builtin_amdgcn_cvt_pk_fp8_f32(a, b, 0, false);
    v = __builtin_amdgcn_cvt_pk_fp8_f32(c, d, v, true);
    return (unsigned)v;
}

// ------- dense: Mt(bf16, transposed [n][k]) = (Wp @ W1)^T -------
__global__ __launch_bounds__(128) void fuse_w(const float* __restrict__ Wp0,
                                              const float* __restrict__ Wp1,
                                              const float* __restrict__ W1,
                                              unsigned short* __restrict__ Mt0,
                                              unsigned short* __restrict__ Mt1) {
    int m = blockIdx.x >> 7;
    int i = blockIdx.x & 127;           // row of M = k index
    const float* Wp = m ? Wp1 : Wp0;
    unsigned short* Mt = m ? Mt1 : Mt0;
    __shared__ float r[128];
    int t = threadIdx.x;
    r[t] = Wp[i * 128 + t];
    __syncthreads();
    float acc = 0.f;
    #pragma unroll 8
    for (int k = 0; k < 128; ++k) acc += r[k] * W1[k * 128 + t];
    Mt[t * 128 + i] = f2bf(acc);        // transposed store: Mt[n][k]
}

// ---- dense (MFMA): Xbf/X8 = normalize(relu(xin @ M + b1)) ----
__global__ __launch_bounds__(256) void gemm_relu_norm(const float* __restrict__ xin,
                                                      const unsigned short* __restrict__ Mt,
                                                      const float* __restrict__ b1,
                                                      unsigned short* __restrict__ xbf,
                                                      unsigned char* __restrict__ x8,
                                                      int nrows) {
    __shared__ char xsh[64 * 256];      // x hi bf16, swizzled 16B slots
    __shared__ char xsl[64 * 256];      // x lo bf16
    __shared__ char mts[128 * 256];     // Mt bf16 [n][k], swizzled
    int t = threadIdx.x;
    long row0 = (long)blockIdx.x * 64;
    int rows_this = nrows - (int)row0;
    if (rows_this > 64) rows_this = 64;

    // stage x: fp32 -> (hi, lo) bf16 split, 16B slots swizzled by row&7
    #pragma unroll
    for (int it = 0; it < 4; ++it) {
        int idx = it * 256 + t;
        int row = idx >> 4, slot = idx & 15;
        float4 v0 = {0.f, 0.f, 0.f, 0.f}, v1 = {0.f, 0.f, 0.f, 0.f};
        if (row < rows_this) {
            v0 = *(const float4*)(xin + (row0 + row) * 128 + slot * 8);
            v1 = *(const float4*)(xin + (row0 + row) * 128 + slot * 8 + 4);
        }
        float vv[8] = {v0.x, v0.y, v0.z, v0.w, v1.x, v1.y, v1.z, v1.w};
        unsigned hw[8], lw[8];
        #pragma unroll
        for (int j = 0; j < 8; ++j) {
            unsigned h = f2bf(vv[j]);
            float hv = __uint_as_float(h << 16);
            hw[j] = h;
            lw[j] = f2bf(vv[j] - hv);
        }
        uint4 ph, pl;
        ph.x = hw[0] | (hw[1] << 16); ph.y = hw[2] | (hw[3] << 16);
        ph.z = hw[4] | (hw[5] << 16); ph.w = hw[6] | (hw[7] << 16);
        pl.x = lw[0] | (lw[1] << 16); pl.y = lw[2] | (lw[3] << 16);
        pl.z = lw[4] | (lw[5] << 16); pl.w = lw[6] | (lw[7] << 16);
        int off = row * 256 + ((slot ^ (row & 7)) << 4);
        *(uint4*)&xsh[off] = ph;
        *(uint4*)&xsl[off] = pl;
    }
    // stage Mt (32 KB, L2-hot), same swizzle
    #pragma unroll
    for (int it = 0; it < 8; ++it) {
        int idx = it * 256 + t;
        int row = idx >> 4, slot = idx & 15;
        uint4 mv = ((const uint4*)Mt)[idx];
        *(uint4*)&mts[row * 256 + ((slot ^ (row & 7)) << 4)] = mv;
    }
    __syncthreads();

    int w = t >> 6;                 // wave id: rows w*16..w*16+15
    int lidx = t & 15;              // lane&15
    int grp = (t >> 4) & 3;         // lane>>4 within wave
    f32x4 acc[8];
    #pragma unroll
    for (int nt = 0; nt < 8; ++nt) acc[nt] = (f32x4){0.f, 0.f, 0.f, 0.f};

    #pragma unroll
    for (int ks = 0; ks < 4; ++ks) {
        int arow = w * 16 + lidx;
        int slot = ks * 4 + grp;
        bf16x8 ah = *(bf16x8*)&xsh[arow * 256 + ((slot ^ (arow & 7)) << 4)];
        bf16x8 al = *(bf16x8*)&xsl[arow * 256 + ((slot ^ (arow & 7)) << 4)];
        #pragma unroll
        for (int nt = 0; nt < 8; ++nt) {
            int brow = nt * 16 + lidx;
            bf16x8 bb = *(bf16x8*)&mts[brow * 256 + ((slot ^ (brow & 7)) << 4)];
            acc[nt] = __builtin_amdgcn_mfma_f32_16x16x32_bf16(al, bb, acc[nt], 0, 0, 0);
            acc[nt] = __builtin_amdgcn_mfma_f32_16x16x32_bf16(ah, bb, acc[nt], 0, 0, 0);
        }
    }

    float bias[8];
    #pragma unroll
    for (int nt = 0; nt < 8; ++nt) bias[nt] = b1[nt * 16 + lidx];

    // epilogue: relu -> mean/std (16-lane group = one row) -> z -> LDS (bf16)
    #pragma unroll
    for (int r = 0; r < 4; ++r) {
        int row_loc = w * 16 + grp * 4 + r;
        float v[8];
        float s = 0.f;
        #pragma unroll
        for (int nt = 0; nt < 8; ++nt) {
            float x = acc[nt][r] + bias[nt];
            x = x > 0.f ? x : 0.f;
            v[nt] = x;
            s += x;
        }
        s += __shfl_xor(s, 1); s += __shfl_xor(s, 2);
        s += __shfl_xor(s, 4); s += __shfl_xor(s, 8);
        float mean = s * (1.0f / 128.0f);
        float q = 0.f;
        #pragma unroll
        for (int nt = 0; nt < 8; ++nt) {
            float d = v[nt] - mean;
            v[nt] = d;
            q += d * d;
        }
        q += __shfl_xor(q, 1); q += __shfl_xor(q, 2);
        q += __shfl_xor(q, 4); q += __shfl_xor(q, 8);
        float inv = 0.f;
        if (q > 0.f) inv = 1.0f / sqrtf(q * (1.0f / 127.0f));
        #pragma unroll
        for (int nt = 0; nt < 8; ++nt)
            *(unsigned short*)&xsh[row_loc * 256 + (nt * 16 + lidx) * 2] = f2bf(v[nt] * inv);
    }
    __syncthreads();

    // coalesced writeout: bf16 row-linear + fp8 shadow
    #pragma unroll
    for (int it = 0; it < 4; ++it) {
        int idx = it * 256 + t;
        int row = idx >> 4, slot = idx & 15;
        if (row < rows_this) {
            uint4 zv = *(uint4*)&xsh[row * 256 + slot * 16];
            *(uint4*)(xbf + (row0 + row) * 128 + slot * 8) = zv;
            uint2 p8;
            p8.x = pk_fp8x4(bflo(zv.x), bfhi(zv.x), bflo(zv.y), bfhi(zv.y));
            p8.y = pk_fp8x4(bflo(zv.z), bfhi(zv.z), bflo(zv.w), bfhi(zv.w));
            *(uint2*)(x8 + (row0 + row) * 128 + slot * 8) = p8;
        }
    }
}

// ---------------- CSR build (unified, N rows, global cols) ----------------
__global__ __launch_bounds__(256) void count_rows(const int* __restrict__ rows, int E,
                                                  int* __restrict__ cnt) {
    int i = (blockIdx.x * 256 + threadIdx.x) * 4;
    if (i + 4 <= E) {
        int4 r = *(const int4*)(rows + i);
        atomicAdd(&cnt[r.x], 1);
        atomicAdd(&cnt[r.y], 1);
        atomicAdd(&cnt[r.z], 1);
        atomicAdd(&cnt[r.w], 1);
    } else {
        for (; i < E; ++i) atomicAdd(&cnt[rows[i]], 1);
    }
}

__global__ __launch_bounds__(256) void scan1(const int* __restrict__ cnt, int R,
                                             int* __restrict__ rp, int* __restrict__ bt) {
    __shared__ int lds[256];
    int t = threadIdx.x, b = blockIdx.x;
    int base = b * 4096 + t * 16;
    int v[16];
    int s = 0;
    #pragma unroll
    for (int i = 0; i < 16; ++i) {
        int idx = base + i;
        int c = (idx < R) ? cnt[idx] : 0;
        v[i] = s;
        s += c;
    }
    lds[t] = s;
    __syncthreads();
    for (int off = 1; off < 256; off <<= 1) {
        int x = (t >= off) ? lds[t - off] : 0;
        __syncthreads();
        lds[t] += x;
        __syncthreads();
    }
    int excl = lds[t] - s;
    #pragma unroll
    for (int i = 0; i < 16; ++i) {
        int idx = base + i;
        if (idx < R) rp[idx] = excl + v[i];
    }
    if (t == 0) bt[b] = lds[255];
}

__global__ __launch_bounds__(64) void scan2(const int* __restrict__ bt, int B,
                                            int* __restrict__ bo, int* __restrict__ rp,
                                            int R, int E2) {
    int t = threadIdx.x;
    int v = (t < B) ? bt[t] : 0;
    int inc = v;
    #pragma unroll
    for (int off = 1; off < 64; off <<= 1) {
        int y = __shfl_up(inc, off);
        if (t >= off) inc += y;
    }
    if (t < B) bo[t] = inc - v;
    if (t == 0) rp[R] = E2;
}

__global__ __launch_bounds__(256) void scan3(int* __restrict__ rp, const int* __restrict__ bo,
                                             int R) {
    int i = blockIdx.x * 256 + threadIdx.x;
    if (i < R) rp[i] = rp[i] + bo[i >> 12];
}

__global__ __launch_bounds__(256) void binit(const int* __restrict__ rp, int NR,
                                             int nbuck, int* __restrict__ bcur) {
    int b = blockIdx.x * 256 + threadIdx.x;
    if (b < nbuck) {
        int r = b << 9;
        if (r > NR) r = NR;
        bcur[b] = rp[r];
    }
}

// ---- degree-sorted row order: 64-bucket counting sort ----
__global__ __launch_bounds__(256) void dhist(const int* __restrict__ rp, int R,
                                             int* __restrict__ dcnt) {
    __shared__ int h[64];
    int t = threadIdx.x;
    if (t < 64) h[t] = 0;
    __syncthreads();
    int i = blockIdx.x * 256 + t;
    if (i < R) {
        int d = rp[i + 1] - rp[i];
        if (d > 63) d = 63;
        atomicAdd(&h[d], 1);
    }
    __syncthreads();
    if (t < 64 && h[t]) atomicAdd(&dcnt[t], h[t]);
}

__global__ __launch_bounds__(64) void dscan(int* __restrict__ dcnt) {
    int t = threadIdx.x;
    int v = dcnt[t];
    int inc = v;
    #pragma unroll
    for (int off = 1; off < 64; off <<= 1) {
        int y = __shfl_up(inc, off);
        if (t >= off) inc += y;
    }
    dcnt[t] = inc - v;     // exclusive prefix -> running cursor
}

__global__ __launch_bounds__(256) void dscatter(const int* __restrict__ rp, int R,
                                                int* __restrict__ dcur,
                                                int* __restrict__ order) {
    __shared__ int h[64], gb[64], c2[64];
    int t = threadIdx.x;
    if (t < 64) { h[t] = 0; c2[t] = 0; }
    __syncthreads();
    int i = blockIdx.x * 256 + t;
    int d = 0;
    if (i < R) {
        d = rp[i + 1] - rp[i];
        if (d > 63) d = 63;
        atomicAdd(&h[d], 1);
    }
    __syncthreads();
    if (t < 64) gb[t] = h[t] ? atomicAdd(&dcur[t], h[t]) : 0;
    __syncthreads();
    if (i < R) {
        int r = atomicAdd(&c2[d], 1);
        order[gb[d] + r] = i;
    }
}

// ---- phase 1: partition edges into 512-row buckets (L2-local writes) ----
__global__ __launch_bounds__(256) void partition_edges(const int* __restrict__ rows,
                                                       const int* __restrict__ cols,
                                                       const float* __restrict__ vals,
                                                       int E, int nbuck,
                                                       int* __restrict__ bcur,
                                                       int2* __restrict__ tmp) {
    __shared__ int hist[512];
    __shared__ int gbase[512];
    __shared__ int cnt2[512];
    int t = threadIdx.x;
    for (int b = t; b < nbuck; b += 256) { hist[b] = 0; cnt2[b] = 0; }
    __syncthreads();
    long base = (long)blockIdx.x * 4096;
    #pragma unroll
    for (int k = 0; k < 16; ++k) {
        long i = base + k * 256 + t;
        if (i < E) atomicAdd(&hist[rows[i] >> 9], 1);
    }
    __syncthreads();
    for (int b = t; b < nbuck; b += 256) {
        int h = hist[b];
        gbase[b] = h ? atomicAdd(&bcur[b], h) : 0;
    }
    __syncthreads();
    #pragma unroll
    for (int k = 0; k < 16; ++k) {
        long i = base + k * 256 + t;
        if (i < E) {
            int rl = rows[i];
            int b = rl >> 9;
            int rank = atomicAdd(&cnt2[b], 1);
            int2 rec;
            rec.x = ((rl - (b << 9)) << 18) | cols[i];
            rec.y = __float_as_int(vals[i]);
            tmp[gbase[b] + rank] = rec;
        }
    }
}

// ---- phase 2: exact-position scatter within one bucket, LDS atomics only ----
__global__ __launch_bounds__(1024) void place_edges(const int* __restrict__ rp,
                                                    const int2* __restrict__ tmp,
                                                    int NR,
                                                    int2* __restrict__ scv) {
    __shared__ int hist[512];
    __shared__ int hoff[512];
    int b = blockIdx.x;
    int srow = b << 9;
    int erow = srow + 512;
    if (erow > NR) erow = NR;
    int start = rp[srow], endp = rp[erow];
    int t = threadIdx.x;
    if (t < 512) hist[t] = 0;
    __syncthreads();

    for (int i = start + t; i < endp; i += 1024)
        atomicAdd(&hist[tmp[i].x >> 18], 1);
    __syncthreads();

    if (t < 512) hoff[t] = hist[t];
    __syncthreads();
    for (int off = 1; off < 512; off <<= 1) {
        int v = 0;
        if (t < 512 && t >= off) v = hoff[t - off];
        __syncthreads();
        if (t < 512) hoff[t] += v;
        __syncthreads();
    }
    if (t < 512) hoff[t] = start + hoff[t] - hist[t];
    __syncthreads();

    int i = start + t;
    for (; i + 3 * 1024 < endp; i += 4 * 1024) {
        int2 a0 = tmp[i];
        int2 a1 = tmp[i + 1024];
        int2 a2 = tmp[i + 2048];
        int2 a3 = tmp[i + 3072];
        int p0 = atomicAdd(&hoff[a0.x >> 18], 1);
        int p1 = atomicAdd(&hoff[a1.x >> 18], 1);
        int p2 = atomicAdd(&hoff[a2.x >> 18], 1);
        int p3 = atomicAdd(&hoff[a3.x >> 18], 1);
        int2 o0; o0.x = a0.x & 0x3ffff; o0.y = a0.y;
        int2 o1; o1.x = a1.x & 0x3ffff; o1.y = a1.y;
        int2 o2; o2.x = a2.x & 0x3ffff; o2.y = a2.y;
        int2 o3; o3.x = a3.x & 0x3ffff; o3.y = a3.y;
        scv[p0] = o0;
        scv[p1] = o1;
        scv[p2] = o2;
        scv[p3] = o3;
    }
    for (; i < endp; i += 1024) {
        int2 rec = tmp[i];
        int p = atomicAdd(&hoff[rec.x >> 18], 1);
        int2 o;
        o.x = rec.x & 0x3ffff;
        o.y = rec.y;
        scv[p] = o;
    }
}

// decode one fp8 row-segment (8 vals in uint2) and packed-fma into acc[4]
#define DEC_FMA(qq, vv) do {                                                        \
    f32x2 vp_ = {(vv), (vv)};                                                       \
    acc[0] = __builtin_elementwise_fma(vp_, __builtin_amdgcn_cvt_pk_f32_fp8((qq).x, false), acc[0]); \
    acc[1] = __builtin_elementwise_fma(vp_, __builtin_amdgcn_cvt_pk_f32_fp8((qq).x, true),  acc[1]); \
    acc[2] = __builtin_elementwise_fma(vp_, __builtin_amdgcn_cvt_pk_f32_fp8((qq).y, false), acc[2]); \
    acc[3] = __builtin_elementwise_fma(vp_, __builtin_amdgcn_cvt_pk_f32_fp8((qq).y, true),  acc[3]); \
} while (0)

// ---- SpMM core: one row per 16-lane quarter, unroll x8, fp8 gathers ----
__device__ inline void spmm_core8(const int* __restrict__ rp,
                                  const int2* __restrict__ scv,
                                  const unsigned char* __restrict__ g8,
                                  int row, int f, f32x2* acc) {
    int beg = rp[row], end = rp[row + 1];
    int j = beg;
    // align to even index so int4 (edge-pair) loads are 16B-aligned
    if ((j & 1) && j < end) {
        int2 r0 = scv[j];
        uint2 q0 = *(const uint2*)(g8 + ((long)r0.x << 7) + f);
        float v0 = __int_as_float(r0.y);
        DEC_FMA(q0, v0);
        ++j;
    }
    for (; j + 8 <= end; j += 8) {
        int4 s01 = *(const int4*)(scv + j);
        int4 s23 = *(const int4*)(scv + j + 2);
        int4 s45 = *(const int4*)(scv + j + 4);
        int4 s67 = *(const int4*)(scv + j + 6);
        uint2 q0 = *(const uint2*)(g8 + ((long)s01.x << 7) + f);
        uint2 q1 = *(const uint2*)(g8 + ((long)s01.z << 7) + f);
        uint2 q2 = *(const uint2*)(g8 + ((long)s23.x << 7) + f);
        uint2 q3 = *(const uint2*)(g8 + ((long)s23.z << 7) + f);
        uint2 q4 = *(const uint2*)(g8 + ((long)s45.x << 7) + f);
        uint2 q5 = *(const uint2*)(g8 + ((long)s45.z << 7) + f);
        uint2 q6 = *(const uint2*)(g8 + ((long)s67.x << 7) + f);
        uint2 q7 = *(const uint2*)(g8 + ((long)s67.z << 7) + f);
        DEC_FMA(q0, __int_as_float(s01.y));
        DEC_FMA(q1, __int_as_float(s01.w));
        DEC_FMA(q2, __int_as_float(s23.y));
        DEC_FMA(q3, __int_as_float(s23.w));
        DEC_FMA(q4, __int_as_float(s45.y));
        DEC_FMA(q5, __int_as_float(s45.w));
        DEC_FMA(q6, __int_as_float(s67.y));
        DEC_FMA(q7, __int_as_float(s67.w));
    }
    for (; j + 2 <= end; j += 2) {
        int4 s01 = *(const int4*)(scv + j);
        uint2 q0 = *(const uint2*)(g8 + ((long)s01.x << 7) + f);
        uint2 q1 = *(const uint2*)(g8 + ((long)s01.z << 7) + f);
        DEC_FMA(q0, __int_as_float(s01.y));
        DEC_FMA(q1, __int_as_float(s01.w));
    }
    if (j < end) {
        int2 r0 = scv[j];
        uint2 q0 = *(const uint2*)(g8 + ((long)r0.x << 7) + f);
        float v0 = __int_as_float(r0.y);
        DEC_FMA(q0, v0);
    }
}

// h = M @ X : gathers X8 (fp8), writes h as bf16 (stream copy) + fp8 (gather copy)
__global__ __launch_bounds__(256) void spmm_plain(const int* __restrict__ rp,
                                                  const int2* __restrict__ scv,
                                                  const unsigned char* __restrict__ x8,
                                                  const int* __restrict__ order,
                                                  unsigned short* __restrict__ houtbf,
                                                  unsigned char* __restrict__ hout8,
                                                  int R) {
    int qi = blockIdx.x * 16 + (threadIdx.x >> 4);
    if (qi >= R) return;
    int row = order[qi];
    int lane = threadIdx.x & 63;
    int f = (lane & 15) << 3;
    f32x2 acc[4];
    #pragma unroll
    for (int i = 0; i < 4; ++i) acc[i] = (f32x2){0.f, 0.f};
    spmm_core8(rp, scv, x8, row, f, acc);
    long o = ((long)row << 7) + f;
    uint4 ob;
    ob.x = (unsigned)f2bf(acc[0].x) | ((unsigned)f2bf(acc[0].y) << 16);
    ob.y = (unsigned)f2bf(acc[1].x) | ((unsigned)f2bf(acc[1].y) << 16);
    ob.z = (unsigned)f2bf(acc[2].x) | ((unsigned)f2bf(acc[2].y) << 16);
    ob.w = (unsigned)f2bf(acc[3].x) | ((unsigned)f2bf(acc[3].y) << 16);
    *(uint4*)(houtbf + o) = ob;
    uint2 o8;
    o8.x = pk_fp8x4(acc[0].x, acc[0].y, acc[1].x, acc[1].y);
    o8.y = pk_fp8x4(acc[2].x, acc[2].y, acc[3].x, acc[3].y);
    *(uint2*)(hout8 + o) = o8;
}

// pass-1 update: X = c0*X + c_h[seg]*h + c_2nd[seg]*(M @ h)
__global__ __launch_bounds__(256) void spmm_update(const int* __restrict__ rp,
                                                   const int2* __restrict__ scv,
                                                   const unsigned char* __restrict__ h8,
                                                   const unsigned short* __restrict__ hbf,
                                                   const int* __restrict__ order,
                                                   unsigned short* __restrict__ Xbf,
                                                   unsigned char* __restrict__ X8,
                                                   const float* __restrict__ coe,
                                                   int ihA, int iaA, int ihP, int iaP,
                                                   int NA, int R) {
    int qi = blockIdx.x * 16 + (threadIdx.x >> 4);
    if (qi >= R) return;
    int row = order[qi];
    int lane = threadIdx.x & 63;
    int f = (lane & 15) << 3;
    f32x2 acc[4];
    #pragma unroll
    for (int i = 0; i < 4; ++i) acc[i] = (f32x2){0.f, 0.f};
    spmm_core8(rp, scv, h8, row, f, acc);

    float c0 = coe[0];
    float ch = coe[row < NA ? ihA : ihP];
    float ca = coe[row < NA ? iaA : iaP];
    long o = ((long)row << 7) + f;
    uint4 xv = *(const uint4*)(Xbf + o);
    uint4 hs = *(const uint4*)(hbf + o);
    float r[8];
    r[0] = c0 * bflo(xv.x) + ch * bflo(hs.x) + ca * acc[0].x;
    r[1] = c0 * bfhi(xv.x) + ch * bfhi(hs.x) + ca * acc[0].y;
    r[2] = c0 * bflo(xv.y) + ch * bflo(hs.y) + ca * acc[1].x;
    r[3] = c0 * bfhi(xv.y) + ch * bfhi(hs.y) + ca * acc[1].y;
    r[4] = c0 * bflo(xv.z) + ch * bflo(hs.z) + ca * acc[2].x;
    r[5] = c0 * bfhi(xv.z) + ch * bfhi(hs.z) + ca * acc[2].y;
    r[6] = c0 * bflo(xv.w) + ch * bflo(hs.w) + ca * acc[3].x;
    r[7] = c0 * bfhi(xv.w) + ch * bfhi(hs.w) + ca * acc[3].y;
    uint4 ob;
    ob.x = (unsigned)f2bf(r[0]) | ((unsigned)f2bf(r[1]) << 16);
    ob.y = (unsigned)f2bf(r[2]) | ((unsigned)f2bf(r[3]) << 16);
    ob.z = (unsigned)f2bf(r[4]) | ((unsigned)f2bf(r[5]) << 16);
    ob.w = (unsigned)f2bf(r[6]) | ((unsigned)f2bf(r[7]) << 16);
    *(uint4*)(Xbf + o) = ob;
    uint2 o8;
    o8.x = pk_fp8x4(r[0], r[1], r[2], r[3]);
    o8.y = pk_fp8x4(r[4], r[5], r[6], r[7]);
    *(uint2*)(X8 + o) = o8;
}

// pass-2 update fused with final GEMM (rows via order[]; out indexed by true row)
__global__ __launch_bounds__(256) void spmm_update_out(const int* __restrict__ rp,
                                                       const int2* __restrict__ scv,
                                                       const unsigned char* __restrict__ h8,
                                                       const unsigned short* __restrict__ hbf,
                                                       const unsigned short* __restrict__ Xbf,
                                                       const int* __restrict__ order,
                                                       const float* __restrict__ coe,
                                                       const float* __restrict__ W2,
                                                       const float* __restrict__ b2,
                                                       float* __restrict__ out,
                                                       int ihA, int iaA, int ihP, int iaP,
                                                       int NA, int R) {
    __shared__ float xs[16 * 132];
    __shared__ float wT[16 * 132];   // wT[c][k] = W2[k][c]
    __shared__ float bs[16];
    int t = threadIdx.x;
    #pragma unroll
    for (int i = 0; i < 8; ++i) {
        int idx = i * 256 + t;                // 2048 = 128*16
        wT[(idx & 15) * 132 + (idx >> 4)] = W2[idx];
    }
    if (t < 16) bs[t] = b2[t];

    int rl = t >> 4;                 // local row slot 0..15
    int qi = blockIdx.x * 16 + rl;
    int lane = t & 63;
    int f = (lane & 15) << 3;
    if (qi < R) {
        int row = order[qi];
        f32x2 acc[4];
        #pragma unroll
        for (int i = 0; i < 4; ++i) acc[i] = (f32x2){0.f, 0.f};
        spmm_core8(rp, scv, h8, row, f, acc);
        float c0 = coe[0];
        float ch = coe[row < NA ? ihA : ihP];
        float ca = coe[row < NA ? iaA : iaP];
        long o = ((long)row << 7) + f;
        uint4 xv = *(const uint4*)(Xbf + o);
        uint4 hs = *(const uint4*)(hbf + o);
        float* x = &xs[rl * 132 + f];
        x[0] = c0 * bflo(xv.x) + ch * bflo(hs.x) + ca * acc[0].x;
        x[1] = c0 * bfhi(xv.x) + ch * bfhi(hs.x) + ca * acc[0].y;
        x[2] = c0 * bflo(xv.y) + ch * bflo(hs.y) + ca * acc[1].x;
        x[3] = c0 * bfhi(xv.y) + ch * bfhi(hs.y) + ca * acc[1].y;
        x[4] = c0 * bflo(xv.z) + ch * bflo(hs.z) + ca * acc[2].x;
        x[5] = c0 * bfhi(xv.z) + ch * bfhi(hs.z) + ca * acc[2].y;
        x[6] = c0 * bflo(xv.w) + ch * bflo(hs.w) + ca * acc[3].x;
        x[7] = c0 * bfhi(xv.w) + ch * bfhi(hs.w) + ca * acc[3].y;
    }
    __syncthreads();
    int orl = t >> 4, c = t & 15;
    int oqi = blockIdx.x * 16 + orl;
    if (oqi < R) {
        long orow = order[oqi];
        const float* xrow = &xs[orl * 132];
        const float* wrow = &wT[c * 132];
        f32x4 a4 = {0.f, 0.f, 0.f, 0.f};
        #pragma unroll 8
        for (int k = 0; k < 128; k += 4) {
            f32x4 xv = *(const f32x4*)(xrow + k);
            f32x4 wv = *(const f32x4*)(wrow + k);
            a4 = __builtin_elementwise_fma(xv, wv, a4);
        }
        out[orow * 16 + c] = a4.x + a4.y + a4.z + a4.w + bs[c];
    }
}

extern "C" void kernel_launch(void* const* d_in, const int* in_sizes, int n_in,
                              void* d_out, int out_size, void* d_ws, size_t ws_size,
                              hipStream_t stream) {
    const float* x0  = (const float*)d_in[0];
    const float* x1  = (const float*)d_in[1];
    const float* vap = (const float*)d_in[2];
    const float* vpa = (const float*)d_in[3];
    const int*   rap = (const int*)d_in[4];
    const int*   cap = (const int*)d_in[5];
    const int*   rpa = (const int*)d_in[6];
    const int*   cpa = (const int*)d_in[7];
    const float* Wp0 = (const float*)d_in[8];
    const float* Wp1 = (const float*)d_in[9];
    const float* W1  = (const float*)d_in[10];
    const float* b1  = (const float*)d_in[11];
    const float* W2  = (const float*)d_in[12];
    const float* b2  = (const float*)d_in[13];
    const float* coe = (const float*)d_in[14];
    float* out = (float*)d_out;

    const int NA = in_sizes[0] / 128;
    const int NP = in_sizes[1] / 128;
    const int N  = NA + NP;
    const int E  = in_sizes[2];
    const int E2 = 2 * E;

    char* p = (char*)d_ws;
    auto alloc = [&](size_t bytes) {
        char* r = p;
        p += (bytes + 255) & ~(size_t)255;
        return r;
    };
    unsigned short* Xbf = (unsigned short*)alloc((size_t)N * 128 * 2);
    unsigned short* hbf = (unsigned short*)alloc((size_t)N * 128 * 2);
    unsigned char* X8 = (unsigned char*)alloc((size_t)N * 128);
    unsigned char* h8 = (unsigned char*)alloc((size_t)N * 128);
    unsigned short* Mt0 = (unsigned short*)alloc(128 * 128 * 2);
    unsigned short* Mt1 = (unsigned short*)alloc(128 * 128 * 2);
    int* cnt   = (int*)alloc((size_t)N * 4);
    int* rp    = (int*)alloc((size_t)(N + 1) * 4);
    int* order = (int*)alloc((size_t)N * 4);
    int* dcnt  = (int*)alloc(64 * 4);
    int* bt    = (int*)alloc(64 * 4);
    int* bo    = (int*)alloc(64 * 4);
    int2* scv  = (int2*)alloc(((size_t)E2 + 8) * 8);
    int* bcur  = (int*)alloc(512 * 4);
    if ((size_t)(p - (char*)d_ws) > ws_size) return;

    // tmp partition buffer aliases Xbf (Xbf written only after CSR build);
    // E2*8 = 32 MB <= N*256B = 64 MB
    int2* tmp = (int2*)Xbf;

    const int nbuck = (N + 511) >> 9;
    const int pg = (E + 4095) / 4096;
    const int ng = (N + 255) / 256;

    // ---- unified CSR build ----
    hipMemsetAsync(cnt, 0, (size_t)N * 4, stream);
    hipMemsetAsync(dcnt, 0, 64 * 4, stream);
    hipMemsetAsync(scv + E2, 0, 8 * sizeof(int2), stream);
    const int cg = (E / 4 + 255) / 256;
    count_rows<<<cg, 256, 0, stream>>>(rap, E, cnt);
    count_rows<<<cg, 256, 0, stream>>>(rpa, E, cnt);
    int B = (N + 4095) / 4096;
    scan1<<<B, 256, 0, stream>>>(cnt, N, rp, bt);
    scan2<<<1, 64, 0, stream>>>(bt, B, bo, rp, N, E2);
    scan3<<<ng, 256, 0, stream>>>(rp, bo, N);
    binit<<<2, 256, 0, stream>>>(rp, N, nbuck, bcur);

    // ---- degree-sorted row order ----
    dhist<<<ng, 256, 0, stream>>>(rp, N, dcnt);
    dscan<<<1, 64, 0, stream>>>(dcnt);
    dscatter<<<ng, 256, 0, stream>>>(rp, N, dcnt, order);

    partition_edges<<<pg, 256, 0, stream>>>(rap, cap, vap, E, nbuck, bcur, tmp);
    partition_edges<<<pg, 256, 0, stream>>>(rpa, cpa, vpa, E, nbuck, bcur, tmp);
    place_edges<<<nbuck, 1024, 0, stream>>>(rp, tmp, N, scv);

    // ---- dense front-end (MFMA; Xbf written AFTER tmp aliasing done) ----
    fuse_w<<<256, 128, 0, stream>>>(Wp0, Wp1, W1, Mt0, Mt1);
    gemm_relu_norm<<<(NA + 63) / 64, 256, 0, stream>>>(x0, Mt0, b1, Xbf, X8, NA);
    gemm_relu_norm<<<(NP + 63) / 64, 256, 0, stream>>>(
        x1, Mt1, b1, Xbf + (size_t)NA * 128, X8 + (size_t)NA * 128, NP);

    const int sg = (N + 15) / 16;

    // ---- pass 1 (AP first): A rows coe1/coe3, P rows coe2/coe4 ----
    spmm_plain<<<sg, 256, 0, stream>>>(rp, scv, X8, order, hbf, h8, N);
    spmm_update<<<sg, 256, 0, stream>>>(rp, scv, h8, hbf, order, Xbf, X8, coe,
                                        1, 3, 2, 4, NA, N);

    // ---- pass 2 (PA first) fused with out = res2 @ W2 + b2 ----
    spmm_plain<<<sg, 256, 0, stream>>>(rp, scv, X8, order, hbf, h8, N);
    spmm_update_out<<<sg, 256, 0, stream>>>(rp, scv, h8, hbf, Xbf, order, coe,
                                            W2, b2, out, 2, 4, 1, 3, NA, N);
}

// Round 10
// 937.749 us; speedup vs baseline: 1.1327x; 1.0434x over previous
//
#include <hip/hip_runtime.h>
#include <hip/hip_bf16.h>

// PSHGCN on MI355X — round 15:
//  * Degree sort made WINDOW-LOCAL (1024 rows). Round-14 post-mortem: global
//    sort fixed balance (rate 2.9->3.76 TB/s, VALU 55->35%) but scattered the
//    row sequence -> FETCH +33 MB / WRITE +31 MB (L2 locality of scv segments
//    and Xbf/hbf/X8 streams destroyed) -> net regression 913->978.
//    Within-window sort keeps quartet balance (1024 iid Poisson rows sort to
//    near-equal neighbors) while all streams stay inside a 256 KB window in
//    natural coarse order. Single block-local kernel replaces the 3-kernel
//    global sort. Per-row math identical -> bitwise-same output.
//  * everything else unchanged from round 14 (round-12 SpMM core, MFMA
//    front-end, LDS-histogram place_edges).

typedef float f32x2 __attribute__((ext_vector_type(2)));
typedef float f32x4 __attribute__((ext_vector_type(4)));
typedef short bf16x8 __attribute__((ext_vector_type(8)));

__device__ inline unsigned short f2bf(float x) {
    unsigned b = __float_as_uint(x);
    unsigned r = (b + 0x7fffu + ((b >> 16) & 1u)) >> 16;
    return (unsigned short)r;
}
__device__ inline float bflo(unsigned u) { return __uint_as_float(u << 16); }
__device__ inline float bfhi(unsigned u) { return __uint_as_float(u & 0xffff0000u); }

// pack 4 floats -> 4 fp8 e4m3 bytes (a in byte0 .. d in byte3)
__device__ inline unsigned pk_fp8x4(float a, float b, float c, float d) {
    int v = __builtin_amdgcn_cvt_pk_fp8_f32(a, b, 0, false);
    v = __builtin_amdgcn_cvt_pk_fp8_f32(c, d, v, true);
    return (unsigned)v;
}

// ------- dense: Mt(bf16, transposed [n][k]) = (Wp @ W1)^T -------
__global__ __launch_bounds__(128) void fuse_w(const float* __restrict__ Wp0,
                                              const float* __restrict__ Wp1,
                                              const float* __restrict__ W1,
                                              unsigned short* __restrict__ Mt0,
                                              unsigned short* __restrict__ Mt1) {
    int m = blockIdx.x >> 7;
    int i = blockIdx.x & 127;           // row of M = k index
    const float* Wp = m ? Wp1 : Wp0;
    unsigned short* Mt = m ? Mt1 : Mt0;
    __shared__ float r[128];
    int t = threadIdx.x;
    r[t] = Wp[i * 128 + t];
    __syncthreads();
    float acc = 0.f;
    #pragma unroll 8
    for (int k = 0; k < 128; ++k) acc += r[k] * W1[k * 128 + t];
    Mt[t * 128 + i] = f2bf(acc);        // transposed store: Mt[n][k]
}

// ---- dense (MFMA): Xbf/X8 = normalize(relu(xin @ M + b1)) ----
__global__ __launch_bounds__(256) void gemm_relu_norm(const float* __restrict__ xin,
                                                      const unsigned short* __restrict__ Mt,
                                                      const float* __restrict__ b1,
                                                      unsigned short* __restrict__ xbf,
                                                      unsigned char* __restrict__ x8,
                                                      int nrows) {
    __shared__ char xsh[64 * 256];      // x hi bf16, swizzled 16B slots
    __shared__ char xsl[64 * 256];      // x lo bf16
    __shared__ char mts[128 * 256];     // Mt bf16 [n][k], swizzled
    int t = threadIdx.x;
    long row0 = (long)blockIdx.x * 64;
    int rows_this = nrows - (int)row0;
    if (rows_this > 64) rows_this = 64;

    // stage x: fp32 -> (hi, lo) bf16 split, 16B slots swizzled by row&7
    #pragma unroll
    for (int it = 0; it < 4; ++it) {
        int idx = it * 256 + t;
        int row = idx >> 4, slot = idx & 15;
        float4 v0 = {0.f, 0.f, 0.f, 0.f}, v1 = {0.f, 0.f, 0.f, 0.f};
        if (row < rows_this) {
            v0 = *(const float4*)(xin + (row0 + row) * 128 + slot * 8);
            v1 = *(const float4*)(xin + (row0 + row) * 128 + slot * 8 + 4);
        }
        float vv[8] = {v0.x, v0.y, v0.z, v0.w, v1.x, v1.y, v1.z, v1.w};
        unsigned hw[8], lw[8];
        #pragma unroll
        for (int j = 0; j < 8; ++j) {
            unsigned h = f2bf(vv[j]);
            float hv = __uint_as_float(h << 16);
            hw[j] = h;
            lw[j] = f2bf(vv[j] - hv);
        }
        uint4 ph, pl;
        ph.x = hw[0] | (hw[1] << 16); ph.y = hw[2] | (hw[3] << 16);
        ph.z = hw[4] | (hw[5] << 16); ph.w = hw[6] | (hw[7] << 16);
        pl.x = lw[0] | (lw[1] << 16); pl.y = lw[2] | (lw[3] << 16);
        pl.z = lw[4] | (lw[5] << 16); pl.w = lw[6] | (lw[7] << 16);
        int off = row * 256 + ((slot ^ (row & 7)) << 4);
        *(uint4*)&xsh[off] = ph;
        *(uint4*)&xsl[off] = pl;
    }
    // stage Mt (32 KB, L2-hot), same swizzle
    #pragma unroll
    for (int it = 0; it < 8; ++it) {
        int idx = it * 256 + t;
        int row = idx >> 4, slot = idx & 15;
        uint4 mv = ((const uint4*)Mt)[idx];
        *(uint4*)&mts[row * 256 + ((slot ^ (row & 7)) << 4)] = mv;
    }
    __syncthreads();

    int w = t >> 6;                 // wave id: rows w*16..w*16+15
    int lidx = t & 15;              // lane&15
    int grp = (t >> 4) & 3;         // lane>>4 within wave
    f32x4 acc[8];
    #pragma unroll
    for (int nt = 0; nt < 8; ++nt) acc[nt] = (f32x4){0.f, 0.f, 0.f, 0.f};

    #pragma unroll
    for (int ks = 0; ks < 4; ++ks) {
        int arow = w * 16 + lidx;
        int slot = ks * 4 + grp;
        bf16x8 ah = *(bf16x8*)&xsh[arow * 256 + ((slot ^ (arow & 7)) << 4)];
        bf16x8 al = *(bf16x8*)&xsl[arow * 256 + ((slot ^ (arow & 7)) << 4)];
        #pragma unroll
        for (int nt = 0; nt < 8; ++nt) {
            int brow = nt * 16 + lidx;
            bf16x8 bb = *(bf16x8*)&mts[brow * 256 + ((slot ^ (brow & 7)) << 4)];
            acc[nt] = __builtin_amdgcn_mfma_f32_16x16x32_bf16(al, bb, acc[nt], 0, 0, 0);
            acc[nt] = __builtin_amdgcn_mfma_f32_16x16x32_bf16(ah, bb, acc[nt], 0, 0, 0);
        }
    }

    float bias[8];
    #pragma unroll
    for (int nt = 0; nt < 8; ++nt) bias[nt] = b1[nt * 16 + lidx];

    // epilogue: relu -> mean/std (16-lane group = one row) -> z -> LDS (bf16)
    #pragma unroll
    for (int r = 0; r < 4; ++r) {
        int row_loc = w * 16 + grp * 4 + r;
        float v[8];
        float s = 0.f;
        #pragma unroll
        for (int nt = 0; nt < 8; ++nt) {
            float x = acc[nt][r] + bias[nt];
            x = x > 0.f ? x : 0.f;
            v[nt] = x;
            s += x;
        }
        s += __shfl_xor(s, 1); s += __shfl_xor(s, 2);
        s += __shfl_xor(s, 4); s += __shfl_xor(s, 8);
        float mean = s * (1.0f / 128.0f);
        float q = 0.f;
        #pragma unroll
        for (int nt = 0; nt < 8; ++nt) {
            float d = v[nt] - mean;
            v[nt] = d;
            q += d * d;
        }
        q += __shfl_xor(q, 1); q += __shfl_xor(q, 2);
        q += __shfl_xor(q, 4); q += __shfl_xor(q, 8);
        float inv = 0.f;
        if (q > 0.f) inv = 1.0f / sqrtf(q * (1.0f / 127.0f));
        #pragma unroll
        for (int nt = 0; nt < 8; ++nt)
            *(unsigned short*)&xsh[row_loc * 256 + (nt * 16 + lidx) * 2] = f2bf(v[nt] * inv);
    }
    __syncthreads();

    // coalesced writeout: bf16 row-linear + fp8 shadow
    #pragma unroll
    for (int it = 0; it < 4; ++it) {
        int idx = it * 256 + t;
        int row = idx >> 4, slot = idx & 15;
        if (row < rows_this) {
            uint4 zv = *(uint4*)&xsh[row * 256 + slot * 16];
            *(uint4*)(xbf + (row0 + row) * 128 + slot * 8) = zv;
            uint2 p8;
            p8.x = pk_fp8x4(bflo(zv.x), bfhi(zv.x), bflo(zv.y), bfhi(zv.y));
            p8.y = pk_fp8x4(bflo(zv.z), bfhi(zv.z), bflo(zv.w), bfhi(zv.w));
            *(uint2*)(x8 + (row0 + row) * 128 + slot * 8) = p8;
        }
    }
}

// ---------------- CSR build (unified, N rows, global cols) ----------------
__global__ __launch_bounds__(256) void count_rows(const int* __restrict__ rows, int E,
                                                  int* __restrict__ cnt) {
    int i = (blockIdx.x * 256 + threadIdx.x) * 4;
    if (i + 4 <= E) {
        int4 r = *(const int4*)(rows + i);
        atomicAdd(&cnt[r.x], 1);
        atomicAdd(&cnt[r.y], 1);
        atomicAdd(&cnt[r.z], 1);
        atomicAdd(&cnt[r.w], 1);
    } else {
        for (; i < E; ++i) atomicAdd(&cnt[rows[i]], 1);
    }
}

__global__ __launch_bounds__(256) void scan1(const int* __restrict__ cnt, int R,
                                             int* __restrict__ rp, int* __restrict__ bt) {
    __shared__ int lds[256];
    int t = threadIdx.x, b = blockIdx.x;
    int base = b * 4096 + t * 16;
    int v[16];
    int s = 0;
    #pragma unroll
    for (int i = 0; i < 16; ++i) {
        int idx = base + i;
        int c = (idx < R) ? cnt[idx] : 0;
        v[i] = s;
        s += c;
    }
    lds[t] = s;
    __syncthreads();
    for (int off = 1; off < 256; off <<= 1) {
        int x = (t >= off) ? lds[t - off] : 0;
        __syncthreads();
        lds[t] += x;
        __syncthreads();
    }
    int excl = lds[t] - s;
    #pragma unroll
    for (int i = 0; i < 16; ++i) {
        int idx = base + i;
        if (idx < R) rp[idx] = excl + v[i];
    }
    if (t == 0) bt[b] = lds[255];
}

__global__ __launch_bounds__(64) void scan2(const int* __restrict__ bt, int B,
                                            int* __restrict__ bo, int* __restrict__ rp,
                                            int R, int E2) {
    int t = threadIdx.x;
    int v = (t < B) ? bt[t] : 0;
    int inc = v;
    #pragma unroll
    for (int off = 1; off < 64; off <<= 1) {
        int y = __shfl_up(inc, off);
        if (t >= off) inc += y;
    }
    if (t < B) bo[t] = inc - v;
    if (t == 0) rp[R] = E2;
}

__global__ __launch_bounds__(256) void scan3(int* __restrict__ rp, const int* __restrict__ bo,
                                             int R) {
    int i = blockIdx.x * 256 + threadIdx.x;
    if (i < R) rp[i] = rp[i] + bo[i >> 12];
}

__global__ __launch_bounds__(256) void binit(const int* __restrict__ rp, int NR,
                                             int nbuck, int* __restrict__ bcur) {
    int b = blockIdx.x * 256 + threadIdx.x;
    if (b < nbuck) {
        int r = b << 9;
        if (r > NR) r = NR;
        bcur[b] = rp[r];
    }
}

// ---- window-local degree sort: one block per 1024-row window ----
// 64-bucket counting sort by CSR degree, entirely in LDS. Quartet balance
// of the global sort, locality of natural order (all streams stay in a
// 256 KB window).
__global__ __launch_bounds__(256) void worder(const int* __restrict__ rp, int R,
                                              int* __restrict__ order) {
    __shared__ int h[64], base[64], c2[64];
    int t = threadIdx.x;
    int w0 = blockIdx.x << 10;
    int wend = w0 + 1024;
    if (wend > R) wend = R;
    if (t < 64) { h[t] = 0; c2[t] = 0; }
    __syncthreads();
    int d[4];
    #pragma unroll
    for (int k = 0; k < 4; ++k) {
        int i = w0 + k * 256 + t;
        int dd = 0;
        if (i < wend) {
            dd = rp[i + 1] - rp[i];
            if (dd > 63) dd = 63;
            atomicAdd(&h[dd], 1);
        }
        d[k] = dd;
    }
    __syncthreads();
    if (t < 64) {
        int v = h[t];
        int inc = v;
        #pragma unroll
        for (int off = 1; off < 64; off <<= 1) {
            int y = __shfl_up(inc, off);
            if (t >= off) inc += y;
        }
        base[t] = inc - v;          // exclusive prefix within window
    }
    __syncthreads();
    #pragma unroll
    for (int k = 0; k < 4; ++k) {
        int i = w0 + k * 256 + t;
        if (i < wend) {
            int r = atomicAdd(&c2[d[k]], 1);
            order[w0 + base[d[k]] + r] = i;
        }
    }
}

// ---- phase 1: partition edges into 512-row buckets (L2-local writes) ----
__global__ __launch_bounds__(256) void partition_edges(const int* __restrict__ rows,
                                                       const int* __restrict__ cols,
                                                       const float* __restrict__ vals,
                                                       int E, int nbuck,
                                                       int* __restrict__ bcur,
                                                       int2* __restrict__ tmp) {
    __shared__ int hist[512];
    __shared__ int gbase[512];
    __shared__ int cnt2[512];
    int t = threadIdx.x;
    for (int b = t; b < nbuck; b += 256) { hist[b] = 0; cnt2[b] = 0; }
    __syncthreads();
    long base = (long)blockIdx.x * 4096;
    #pragma unroll
    for (int k = 0; k < 16; ++k) {
        long i = base + k * 256 + t;
        if (i < E) atomicAdd(&hist[rows[i] >> 9], 1);
    }
    __syncthreads();
    for (int b = t; b < nbuck; b += 256) {
        int h = hist[b];
        gbase[b] = h ? atomicAdd(&bcur[b], h) : 0;
    }
    __syncthreads();
    #pragma unroll
    for (int k = 0; k < 16; ++k) {
        long i = base + k * 256 + t;
        if (i < E) {
            int rl = rows[i];
            int b = rl >> 9;
            int rank = atomicAdd(&cnt2[b], 1);
            int2 rec;
            rec.x = ((rl - (b << 9)) << 18) | cols[i];
            rec.y = __float_as_int(vals[i]);
            tmp[gbase[b] + rank] = rec;
        }
    }
}

// ---- phase 2: exact-position scatter within one bucket, LDS atomics only ----
__global__ __launch_bounds__(1024) void place_edges(const int* __restrict__ rp,
                                                    const int2* __restrict__ tmp,
                                                    int NR,
                                                    int2* __restrict__ scv) {
    __shared__ int hist[512];
    __shared__ int hoff[512];
    int b = blockIdx.x;
    int srow = b << 9;
    int erow = srow + 512;
    if (erow > NR) erow = NR;
    int start = rp[srow], endp = rp[erow];
    int t = threadIdx.x;
    if (t < 512) hist[t] = 0;
    __syncthreads();

    for (int i = start + t; i < endp; i += 1024)
        atomicAdd(&hist[tmp[i].x >> 18], 1);
    __syncthreads();

    if (t < 512) hoff[t] = hist[t];
    __syncthreads();
    for (int off = 1; off < 512; off <<= 1) {
        int v = 0;
        if (t < 512 && t >= off) v = hoff[t - off];
        __syncthreads();
        if (t < 512) hoff[t] += v;
        __syncthreads();
    }
    if (t < 512) hoff[t] = start + hoff[t] - hist[t];
    __syncthreads();

    int i = start + t;
    for (; i + 3 * 1024 < endp; i += 4 * 1024) {
        int2 a0 = tmp[i];
        int2 a1 = tmp[i + 1024];
        int2 a2 = tmp[i + 2048];
        int2 a3 = tmp[i + 3072];
        int p0 = atomicAdd(&hoff[a0.x >> 18], 1);
        int p1 = atomicAdd(&hoff[a1.x >> 18], 1);
        int p2 = atomicAdd(&hoff[a2.x >> 18], 1);
        int p3 = atomicAdd(&hoff[a3.x >> 18], 1);
        int2 o0; o0.x = a0.x & 0x3ffff; o0.y = a0.y;
        int2 o1; o1.x = a1.x & 0x3ffff; o1.y = a1.y;
        int2 o2; o2.x = a2.x & 0x3ffff; o2.y = a2.y;
        int2 o3; o3.x = a3.x & 0x3ffff; o3.y = a3.y;
        scv[p0] = o0;
        scv[p1] = o1;
        scv[p2] = o2;
        scv[p3] = o3;
    }
    for (; i < endp; i += 1024) {
        int2 rec = tmp[i];
        int p = atomicAdd(&hoff[rec.x >> 18], 1);
        int2 o;
        o.x = rec.x & 0x3ffff;
        o.y = rec.y;
        scv[p] = o;
    }
}

// decode one fp8 row-segment (8 vals in uint2) and packed-fma into acc[4]
#define DEC_FMA(qq, vv) do {                                                        \
    f32x2 vp_ = {(vv), (vv)};                                                       \
    acc[0] = __builtin_elementwise_fma(vp_, __builtin_amdgcn_cvt_pk_f32_fp8((qq).x, false), acc[0]); \
    acc[1] = __builtin_elementwise_fma(vp_, __builtin_amdgcn_cvt_pk_f32_fp8((qq).x, true),  acc[1]); \
    acc[2] = __builtin_elementwise_fma(vp_, __builtin_amdgcn_cvt_pk_f32_fp8((qq).y, false), acc[2]); \
    acc[3] = __builtin_elementwise_fma(vp_, __builtin_amdgcn_cvt_pk_f32_fp8((qq).y, true),  acc[3]); \
} while (0)

// ---- SpMM core: one row per 16-lane quarter, unroll x8, fp8 gathers ----
__device__ inline void spmm_core8(const int* __restrict__ rp,
                                  const int2* __restrict__ scv,
                                  const unsigned char* __restrict__ g8,
                                  int row, int f, f32x2* acc) {
    int beg = rp[row], end = rp[row + 1];
    int j = beg;
    // align to even index so int4 (edge-pair) loads are 16B-aligned
    if ((j & 1) && j < end) {
        int2 r0 = scv[j];
        uint2 q0 = *(const uint2*)(g8 + ((long)r0.x << 7) + f);
        float v0 = __int_as_float(r0.y);
        DEC_FMA(q0, v0);
        ++j;
    }
    for (; j + 8 <= end; j += 8) {
        int4 s01 = *(const int4*)(scv + j);
        int4 s23 = *(const int4*)(scv + j + 2);
        int4 s45 = *(const int4*)(scv + j + 4);
        int4 s67 = *(const int4*)(scv + j + 6);
        uint2 q0 = *(const uint2*)(g8 + ((long)s01.x << 7) + f);
        uint2 q1 = *(const uint2*)(g8 + ((long)s01.z << 7) + f);
        uint2 q2 = *(const uint2*)(g8 + ((long)s23.x << 7) + f);
        uint2 q3 = *(const uint2*)(g8 + ((long)s23.z << 7) + f);
        uint2 q4 = *(const uint2*)(g8 + ((long)s45.x << 7) + f);
        uint2 q5 = *(const uint2*)(g8 + ((long)s45.z << 7) + f);
        uint2 q6 = *(const uint2*)(g8 + ((long)s67.x << 7) + f);
        uint2 q7 = *(const uint2*)(g8 + ((long)s67.z << 7) + f);
        DEC_FMA(q0, __int_as_float(s01.y));
        DEC_FMA(q1, __int_as_float(s01.w));
        DEC_FMA(q2, __int_as_float(s23.y));
        DEC_FMA(q3, __int_as_float(s23.w));
        DEC_FMA(q4, __int_as_float(s45.y));
        DEC_FMA(q5, __int_as_float(s45.w));
        DEC_FMA(q6, __int_as_float(s67.y));
        DEC_FMA(q7, __int_as_float(s67.w));
    }
    for (; j + 2 <= end; j += 2) {
        int4 s01 = *(const int4*)(scv + j);
        uint2 q0 = *(const uint2*)(g8 + ((long)s01.x << 7) + f);
        uint2 q1 = *(const uint2*)(g8 + ((long)s01.z << 7) + f);
        DEC_FMA(q0, __int_as_float(s01.y));
        DEC_FMA(q1, __int_as_float(s01.w));
    }
    if (j < end) {
        int2 r0 = scv[j];
        uint2 q0 = *(const uint2*)(g8 + ((long)r0.x << 7) + f);
        float v0 = __int_as_float(r0.y);
        DEC_FMA(q0, v0);
    }
}

// h = M @ X : gathers X8 (fp8), writes h as bf16 (stream copy) + fp8 (gather copy)
__global__ __launch_bounds__(256) void spmm_plain(const int* __restrict__ rp,
                                                  const int2* __restrict__ scv,
                                                  const unsigned char* __restrict__ x8,
                                                  const int* __restrict__ order,
                                                  unsigned short* __restrict__ houtbf,
                                                  unsigned char* __restrict__ hout8,
                                                  int R) {
    int qi = blockIdx.x * 16 + (threadIdx.x >> 4);
    if (qi >= R) return;
    int row = order[qi];
    int lane = threadIdx.x & 63;
    int f = (lane & 15) << 3;
    f32x2 acc[4];
    #pragma unroll
    for (int i = 0; i < 4; ++i) acc[i] = (f32x2){0.f, 0.f};
    spmm_core8(rp, scv, x8, row, f, acc);
    long o = ((long)row << 7) + f;
    uint4 ob;
    ob.x = (unsigned)f2bf(acc[0].x) | ((unsigned)f2bf(acc[0].y) << 16);
    ob.y = (unsigned)f2bf(acc[1].x) | ((unsigned)f2bf(acc[1].y) << 16);
    ob.z = (unsigned)f2bf(acc[2].x) | ((unsigned)f2bf(acc[2].y) << 16);
    ob.w = (unsigned)f2bf(acc[3].x) | ((unsigned)f2bf(acc[3].y) << 16);
    *(uint4*)(houtbf + o) = ob;
    uint2 o8;
    o8.x = pk_fp8x4(acc[0].x, acc[0].y, acc[1].x, acc[1].y);
    o8.y = pk_fp8x4(acc[2].x, acc[2].y, acc[3].x, acc[3].y);
    *(uint2*)(hout8 + o) = o8;
}

// pass-1 update: X = c0*X + c_h[seg]*h + c_2nd[seg]*(M @ h)
__global__ __launch_bounds__(256) void spmm_update(const int* __restrict__ rp,
                                                   const int2* __restrict__ scv,
                                                   const unsigned char* __restrict__ h8,
                                                   const unsigned short* __restrict__ hbf,
                                                   const int* __restrict__ order,
                                                   unsigned short* __restrict__ Xbf,
                                                   unsigned char* __restrict__ X8,
                                                   const float* __restrict__ coe,
                                                   int ihA, int iaA, int ihP, int iaP,
                                                   int NA, int R) {
    int qi = blockIdx.x * 16 + (threadIdx.x >> 4);
    if (qi >= R) return;
    int row = order[qi];
    int lane = threadIdx.x & 63;
    int f = (lane & 15) << 3;
    f32x2 acc[4];
    #pragma unroll
    for (int i = 0; i < 4; ++i) acc[i] = (f32x2){0.f, 0.f};
    spmm_core8(rp, scv, h8, row, f, acc);

    float c0 = coe[0];
    float ch = coe[row < NA ? ihA : ihP];
    float ca = coe[row < NA ? iaA : iaP];
    long o = ((long)row << 7) + f;
    uint4 xv = *(const uint4*)(Xbf + o);
    uint4 hs = *(const uint4*)(hbf + o);
    float r[8];
    r[0] = c0 * bflo(xv.x) + ch * bflo(hs.x) + ca * acc[0].x;
    r[1] = c0 * bfhi(xv.x) + ch * bfhi(hs.x) + ca * acc[0].y;
    r[2] = c0 * bflo(xv.y) + ch * bflo(hs.y) + ca * acc[1].x;
    r[3] = c0 * bfhi(xv.y) + ch * bfhi(hs.y) + ca * acc[1].y;
    r[4] = c0 * bflo(xv.z) + ch * bflo(hs.z) + ca * acc[2].x;
    r[5] = c0 * bfhi(xv.z) + ch * bfhi(hs.z) + ca * acc[2].y;
    r[6] = c0 * bflo(xv.w) + ch * bflo(hs.w) + ca * acc[3].x;
    r[7] = c0 * bfhi(xv.w) + ch * bfhi(hs.w) + ca * acc[3].y;
    uint4 ob;
    ob.x = (unsigned)f2bf(r[0]) | ((unsigned)f2bf(r[1]) << 16);
    ob.y = (unsigned)f2bf(r[2]) | ((unsigned)f2bf(r[3]) << 16);
    ob.z = (unsigned)f2bf(r[4]) | ((unsigned)f2bf(r[5]) << 16);
    ob.w = (unsigned)f2bf(r[6]) | ((unsigned)f2bf(r[7]) << 16);
    *(uint4*)(Xbf + o) = ob;
    uint2 o8;
    o8.x = pk_fp8x4(r[0], r[1], r[2], r[3]);
    o8.y = pk_fp8x4(r[4], r[5], r[6], r[7]);
    *(uint2*)(X8 + o) = o8;
}

// pass-2 update fused with final GEMM (rows via order[]; out indexed by true row)
__global__ __launch_bounds__(256) void spmm_update_out(const int* __restrict__ rp,
                                                       const int2* __restrict__ scv,
                                                       const unsigned char* __restrict__ h8,
                                                       const unsigned short* __restrict__ hbf,
                                                       const unsigned short* __restrict__ Xbf,
                                                       const int* __restrict__ order,
                                                       const float* __restrict__ coe,
                                                       const float* __restrict__ W2,
                                                       const float* __restrict__ b2,
                                                       float* __restrict__ out,
                                                       int ihA, int iaA, int ihP, int iaP,
                                                       int NA, int R) {
    __shared__ float xs[16 * 132];
    __shared__ float wT[16 * 132];   // wT[c][k] = W2[k][c]
    __shared__ float bs[16];
    int t = threadIdx.x;
    #pragma unroll
    for (int i = 0; i < 8; ++i) {
        int idx = i * 256 + t;                // 2048 = 128*16
        wT[(idx & 15) * 132 + (idx >> 4)] = W2[idx];
    }
    if (t < 16) bs[t] = b2[t];

    int rl = t >> 4;                 // local row slot 0..15
    int qi = blockIdx.x * 16 + rl;
    int lane = t & 63;
    int f = (lane & 15) << 3;
    if (qi < R) {
        int row = order[qi];
        f32x2 acc[4];
        #pragma unroll
        for (int i = 0; i < 4; ++i) acc[i] = (f32x2){0.f, 0.f};
        spmm_core8(rp, scv, h8, row, f, acc);
        float c0 = coe[0];
        float ch = coe[row < NA ? ihA : ihP];
        float ca = coe[row < NA ? iaA : iaP];
        long o = ((long)row << 7) + f;
        uint4 xv = *(const uint4*)(Xbf + o);
        uint4 hs = *(const uint4*)(hbf + o);
        float* x = &xs[rl * 132 + f];
        x[0] = c0 * bflo(xv.x) + ch * bflo(hs.x) + ca * acc[0].x;
        x[1] = c0 * bfhi(xv.x) + ch * bfhi(hs.x) + ca * acc[0].y;
        x[2] = c0 * bflo(xv.y) + ch * bflo(hs.y) + ca * acc[1].x;
        x[3] = c0 * bfhi(xv.y) + ch * bfhi(hs.y) + ca * acc[1].y;
        x[4] = c0 * bflo(xv.z) + ch * bflo(hs.z) + ca * acc[2].x;
        x[5] = c0 * bfhi(xv.z) + ch * bfhi(hs.z) + ca * acc[2].y;
        x[6] = c0 * bflo(xv.w) + ch * bflo(hs.w) + ca * acc[3].x;
        x[7] = c0 * bfhi(xv.w) + ch * bfhi(hs.w) + ca * acc[3].y;
    }
    __syncthreads();
    int orl = t >> 4, c = t & 15;
    int oqi = blockIdx.x * 16 + orl;
    if (oqi < R) {
        long orow = order[oqi];
        const float* xrow = &xs[orl * 132];
        const float* wrow = &wT[c * 132];
        f32x4 a4 = {0.f, 0.f, 0.f, 0.f};
        #pragma unroll 8
        for (int k = 0; k < 128; k += 4) {
            f32x4 xv = *(const f32x4*)(xrow + k);
            f32x4 wv = *(const f32x4*)(wrow + k);
            a4 = __builtin_elementwise_fma(xv, wv, a4);
        }
        out[orow * 16 + c] = a4.x + a4.y + a4.z + a4.w + bs[c];
    }
}

extern "C" void kernel_launch(void* const* d_in, const int* in_sizes, int n_in,
                              void* d_out, int out_size, void* d_ws, size_t ws_size,
                              hipStream_t stream) {
    const float* x0  = (const float*)d_in[0];
    const float* x1  = (const float*)d_in[1];
    const float* vap = (const float*)d_in[2];
    const float* vpa = (const float*)d_in[3];
    const int*   rap = (const int*)d_in[4];
    const int*   cap = (const int*)d_in[5];
    const int*   rpa = (const int*)d_in[6];
    const int*   cpa = (const int*)d_in[7];
    const float* Wp0 = (const float*)d_in[8];
    const float* Wp1 = (const float*)d_in[9];
    const float* W1  = (const float*)d_in[10];
    const float* b1  = (const float*)d_in[11];
    const float* W2  = (const float*)d_in[12];
    const float* b2  = (const float*)d_in[13];
    const float* coe = (const float*)d_in[14];
    float* out = (float*)d_out;

    const int NA = in_sizes[0] / 128;
    const int NP = in_sizes[1] / 128;
    const int N  = NA + NP;
    const int E  = in_sizes[2];
    const int E2 = 2 * E;

    char* p = (char*)d_ws;
    auto alloc = [&](size_t bytes) {
        char* r = p;
        p += (bytes + 255) & ~(size_t)255;
        return r;
    };
    unsigned short* Xbf = (unsigned short*)alloc((size_t)N * 128 * 2);
    unsigned short* hbf = (unsigned short*)alloc((size_t)N * 128 * 2);
    unsigned char* X8 = (unsigned char*)alloc((size_t)N * 128);
    unsigned char* h8 = (unsigned char*)alloc((size_t)N * 128);
    unsigned short* Mt0 = (unsigned short*)alloc(128 * 128 * 2);
    unsigned short* Mt1 = (unsigned short*)alloc(128 * 128 * 2);
    int* cnt   = (int*)alloc((size_t)N * 4);
    int* rp    = (int*)alloc((size_t)(N + 1) * 4);
    int* order = (int*)alloc((size_t)N * 4);
    int* bt    = (int*)alloc(64 * 4);
    int* bo    = (int*)alloc(64 * 4);
    int2* scv  = (int2*)alloc(((size_t)E2 + 8) * 8);
    int* bcur  = (int*)alloc(512 * 4);
    if ((size_t)(p - (char*)d_ws) > ws_size) return;

    // tmp partition buffer aliases Xbf (Xbf written only after CSR build);
    // E2*8 = 32 MB <= N*256B = 64 MB
    int2* tmp = (int2*)Xbf;

    const int nbuck = (N + 511) >> 9;
    const int pg = (E + 4095) / 4096;
    const int ng = (N + 255) / 256;

    // ---- unified CSR build ----
    hipMemsetAsync(cnt, 0, (size_t)N * 4, stream);
    hipMemsetAsync(scv + E2, 0, 8 * sizeof(int2), stream);
    const int cg = (E / 4 + 255) / 256;
    count_rows<<<cg, 256, 0, stream>>>(rap, E, cnt);
    count_rows<<<cg, 256, 0, stream>>>(rpa, E, cnt);
    int B = (N + 4095) / 4096;
    scan1<<<B, 256, 0, stream>>>(cnt, N, rp, bt);
    scan2<<<1, 64, 0, stream>>>(bt, B, bo, rp, N, E2);
    scan3<<<ng, 256, 0, stream>>>(rp, bo, N);
    binit<<<2, 256, 0, stream>>>(rp, N, nbuck, bcur);

    // ---- window-local degree order (1024-row windows) ----
    worder<<<(N + 1023) / 1024, 256, 0, stream>>>(rp, N, order);

    partition_edges<<<pg, 256, 0, stream>>>(rap, cap, vap, E, nbuck, bcur, tmp);
    partition_edges<<<pg, 256, 0, stream>>>(rpa, cpa, vpa, E, nbuck, bcur, tmp);
    place_edges<<<nbuck, 1024, 0, stream>>>(rp, tmp, N, scv);

    // ---- dense front-end (MFMA; Xbf written AFTER tmp aliasing done) ----
    fuse_w<<<256, 128, 0, stream>>>(Wp0, Wp1, W1, Mt0, Mt1);
    gemm_relu_norm<<<(NA + 63) / 64, 256, 0, stream>>>(x0, Mt0, b1, Xbf, X8, NA);
    gemm_relu_norm<<<(NP + 63) / 64, 256, 0, stream>>>(
        x1, Mt1, b1, Xbf + (size_t)NA * 128, X8 + (size_t)NA * 128, NP);

    const int sg = (N + 15) / 16;

    // ---- pass 1 (AP first): A rows coe1/coe3, P rows coe2/coe4 ----
    spmm_plain<<<sg, 256, 0, stream>>>(rp, scv, X8, order, hbf, h8, N);
    spmm_update<<<sg, 256, 0, stream>>>(rp, scv, h8, hbf, order, Xbf, X8, coe,
                                        1, 3, 2, 4, NA, N);

    // ---- pass 2 (PA first) fused with out = res2 @ W2 + b2 ----
    spmm_plain<<<sg, 256, 0, stream>>>(rp, scv, X8, order, hbf, h8, N);
    spmm_update_out<<<sg, 256, 0, stream>>>(rp, scv, h8, hbf, Xbf, order, coe,
                                            W2, b2, out, 2, 4, 1, 3, NA, N);
}